// Round 2
// baseline (340.315 us; speedup 1.0000x reference)
//
#include <hip/hip_runtime.h>
#include <hip/hip_bf16.h>

// ---------------------------------------------------------------------------
// GCN 2-layer fused pipeline, f32 baseline.
//   layer1: ax = A_norm @ x            (aggregate FIRST: 256-wide, linearity)
//           h1 = ax @ W1 + b1 ; h1 = relu(LN(h1, g1, be1))
//   layer2: h2 = h1 @ W2               (aggregate AFTER: 256-wide)
//           a2 = A_norm @ h2 + b2 ; out = relu(LN(a2, g2, be2))
// A_norm row d = sum_{e: dst=d} dinv[src]dinv[d] * row(src) + dinv[d]^2 row(d)
// deg[d] = (#edges into d) + 1 (self loop), dinv = rsqrt(deg).
// ---------------------------------------------------------------------------

__device__ __forceinline__ void wave_reduce2(float& s, float& ss) {
#pragma unroll
  for (int off = 32; off > 0; off >>= 1) {
    s  += __shfl_down(s, off, 64);
    ss += __shfl_down(ss, off, 64);
  }
}

__global__ __launch_bounds__(256) void deg_kernel(const int* __restrict__ dst, int E,
                                                  int* __restrict__ deg) {
  int e = blockIdx.x * 256 + threadIdx.x;
  if (e < E) atomicAdd(&deg[dst[e]], 1);
}

__global__ __launch_bounds__(256) void dinv_kernel(const int* __restrict__ deg, int N,
                                                   float* __restrict__ dinv) {
  int i = blockIdx.x * 256 + threadIdx.x;
  if (i < N) dinv[i] = rsqrtf((float)(deg[i] + 1));  // +1 self loop; always >= 1
}

// exclusive scan of deg[0..N) into offsets[0..N], single block of 1024.
__global__ __launch_bounds__(1024) void scan_kernel(const int* __restrict__ deg, int N,
                                                    int* __restrict__ offsets) {
  __shared__ int sh[1024];
  __shared__ int base_sh;
  int tid = threadIdx.x;
  if (tid == 0) base_sh = 0;
  __syncthreads();
  for (int c = 0; c < N; c += 1024) {
    int v = (c + tid < N) ? deg[c + tid] : 0;
    sh[tid] = v;
    __syncthreads();
    for (int off = 1; off < 1024; off <<= 1) {
      int t = (tid >= off) ? sh[tid - off] : 0;
      __syncthreads();
      sh[tid] += t;
      __syncthreads();
    }
    if (c + tid < N) offsets[c + tid] = base_sh + sh[tid] - v;
    __syncthreads();
    if (tid == 0) base_sh += sh[1023];
    __syncthreads();
  }
  if (tid == 0) offsets[N] = base_sh;
}

__global__ __launch_bounds__(256) void fill_kernel(const int* __restrict__ src,
                                                   const int* __restrict__ dst, int E,
                                                   const int* __restrict__ offsets,
                                                   int* __restrict__ cursor,
                                                   const float* __restrict__ dinv,
                                                   int* __restrict__ csr_src,
                                                   float* __restrict__ csr_norm) {
  int e = blockIdx.x * 256 + threadIdx.x;
  if (e >= E) return;
  int s = src[e], d = dst[e];
  int p = offsets[d] + atomicAdd(&cursor[d], 1);
  csr_src[p]  = s;
  csr_norm[p] = dinv[s] * dinv[d];
}

// one block (256 threads) per node, C = 256 fixed. bias nullable.
__global__ __launch_bounds__(256) void agg256_kernel(const float* __restrict__ H,
                                                     const int* __restrict__ csr_src,
                                                     const float* __restrict__ csr_norm,
                                                     const int* __restrict__ offsets,
                                                     const float* __restrict__ dinv,
                                                     const float* __restrict__ bias,
                                                     float* __restrict__ out) {
  int node = blockIdx.x;
  int c = threadIdx.x;
  float dn = dinv[node];
  float acc = H[(size_t)node * 256 + c] * dn * dn;  // self loop
  int p0 = offsets[node], p1 = offsets[node + 1];
  for (int p = p0; p < p1; ++p) {
    int s   = csr_src[p];   // block-uniform -> scalar load
    float w = csr_norm[p];
    acc = fmaf(H[(size_t)s * 256 + c], w, acc);
  }
  if (bias) acc += bias[c];
  out[(size_t)node * 256 + c] = acc;
}

// f32 tiled GEMM: C[M,N] = A[M,K] @ B[K,N] (+bias). 128x64 tile, 8x4/thread.
#define BM 128
#define BN 64
#define BK 16
__global__ __launch_bounds__(256) void gemm_kernel(const float* __restrict__ A,
                                                   const float* __restrict__ B,
                                                   const float* __restrict__ bias,
                                                   float* __restrict__ C,
                                                   int M, int K, int N) {
  __shared__ float As[BK][BM];
  __shared__ float Bs[BK][BN];
  int tid = threadIdx.x;
  int bm = blockIdx.x * BM;
  int bn = blockIdx.y * BN;
  int tm = (tid >> 4) << 3;   // 0..120 step 8
  int tn = (tid & 15) << 2;   // 0..60 step 4
  int ar = tid >> 2;          // 0..63
  int ak = (tid & 3) << 2;    // 0,4,8,12
  int bk = tid >> 4;          // 0..15
  int bn2 = (tid & 15) << 2;
  float acc[8][4] = {};
  for (int k0 = 0; k0 < K; k0 += BK) {
#pragma unroll
    for (int h = 0; h < 2; ++h) {
      int row = bm + ar + h * 64;
      float4 a = make_float4(0.f, 0.f, 0.f, 0.f);
      if (row < M) a = *(const float4*)&A[(size_t)row * K + k0 + ak];
      As[ak + 0][ar + h * 64] = a.x;
      As[ak + 1][ar + h * 64] = a.y;
      As[ak + 2][ar + h * 64] = a.z;
      As[ak + 3][ar + h * 64] = a.w;
    }
    *(float4*)&Bs[bk][bn2] = *(const float4*)&B[(size_t)(k0 + bk) * N + bn + bn2];
    __syncthreads();
#pragma unroll
    for (int k = 0; k < BK; ++k) {
      float4 a0 = *(const float4*)&As[k][tm];
      float4 a1 = *(const float4*)&As[k][tm + 4];
      float4 b0 = *(const float4*)&Bs[k][tn];
      float av[8] = {a0.x, a0.y, a0.z, a0.w, a1.x, a1.y, a1.z, a1.w};
      float bv[4] = {b0.x, b0.y, b0.z, b0.w};
#pragma unroll
      for (int i = 0; i < 8; ++i)
#pragma unroll
        for (int j = 0; j < 4; ++j) acc[i][j] = fmaf(av[i], bv[j], acc[i][j]);
    }
    __syncthreads();
  }
#pragma unroll
  for (int i = 0; i < 8; ++i) {
    int row = bm + tm + i;
    if (row < M) {
      float4 o;
      o.x = acc[i][0]; o.y = acc[i][1]; o.z = acc[i][2]; o.w = acc[i][3];
      if (bias) {
        o.x += bias[bn + tn + 0]; o.y += bias[bn + tn + 1];
        o.z += bias[bn + tn + 2]; o.w += bias[bn + tn + 3];
      }
      *(float4*)&C[(size_t)row * N + bn + tn] = o;
    }
  }
}

template <int C>
__global__ __launch_bounds__(256) void ln_relu_kernel(const float* __restrict__ in,
                                                      const float* __restrict__ gamma,
                                                      const float* __restrict__ beta,
                                                      float* __restrict__ out) {
  int row = blockIdx.x;
  const float* p = in + (size_t)row * C;
  int tid = threadIdx.x;
  float v0 = p[tid];
  float v1 = (C == 512) ? p[tid + 256] : 0.0f;
  float s = v0 + v1;
  float ss = v0 * v0 + v1 * v1;
  wave_reduce2(s, ss);
  __shared__ float sh[8];
  int wid = tid >> 6;
  if ((tid & 63) == 0) { sh[wid] = s; sh[4 + wid] = ss; }
  __syncthreads();
  s  = sh[0] + sh[1] + sh[2] + sh[3];
  ss = sh[4] + sh[5] + sh[6] + sh[7];
  float mu = s * (1.0f / C);
  float var = ss * (1.0f / C) - mu * mu;
  float r = rsqrtf(var + 1e-5f);
  float o0 = fmaxf((v0 - mu) * r * gamma[tid] + beta[tid], 0.0f);
  out[(size_t)row * C + tid] = o0;
  if (C == 512) {
    float o1 = fmaxf((v1 - mu) * r * gamma[tid + 256] + beta[tid + 256], 0.0f);
    out[(size_t)row * C + tid + 256] = o1;
  }
}

extern "C" void kernel_launch(void* const* d_in, const int* in_sizes, int n_in,
                              void* d_out, int out_size, void* d_ws, size_t ws_size,
                              hipStream_t stream) {
  const float* x    = (const float*)d_in[0];
  const int*   ei   = (const int*)d_in[1];
  const float* W1   = (const float*)d_in[2];
  const float* b1   = (const float*)d_in[3];
  const float* ga1  = (const float*)d_in[4];
  const float* be1  = (const float*)d_in[5];
  const float* W2   = (const float*)d_in[6];
  const float* b2   = (const float*)d_in[7];
  const float* ga2  = (const float*)d_in[8];
  const float* be2  = (const float*)d_in[9];
  float* out = (float*)d_out;

  const int Ch   = in_sizes[3];        // 512
  const int Cout = in_sizes[7];        // 256
  const int Cin  = in_sizes[2] / Ch;   // 256
  const int N    = in_sizes[0] / Cin;  // 10000
  const int E    = in_sizes[1] / 2;    // 160000
  const int* srcp = ei;
  const int* dstp = ei + E;

  char* ws = (char*)d_ws;
  size_t off = 0;
  auto alloc = [&](size_t bytes) -> void* {
    off = (off + 255) & ~(size_t)255;
    void* p = ws + off;
    off += bytes;
    return p;
  };
  float* ax    = (float*)alloc((size_t)N * Cin * 4);  // agg(x); reused as h2
  float* h1    = (float*)alloc((size_t)N * Ch * 4);   // gemm1 out / ln1 / agg2 out
  int*   deg   = (int*)alloc((size_t)N * 4);
  int*   curs  = (int*)alloc((size_t)N * 4);
  int*   offs  = (int*)alloc((size_t)(N + 1) * 4);
  float* dinv  = (float*)alloc((size_t)N * 4);
  int*   csr_s = (int*)alloc((size_t)E * 4);
  float* csr_n = (float*)alloc((size_t)E * 4);

  hipMemsetAsync(deg, 0, (size_t)N * 4, stream);
  hipMemsetAsync(curs, 0, (size_t)N * 4, stream);

  int gE = (E + 255) / 256;
  int gN = (N + 255) / 256;
  deg_kernel<<<gE, 256, 0, stream>>>(dstp, E, deg);
  dinv_kernel<<<gN, 256, 0, stream>>>(deg, N, dinv);
  scan_kernel<<<1, 1024, 0, stream>>>(deg, N, offs);
  fill_kernel<<<gE, 256, 0, stream>>>(srcp, dstp, E, offs, curs, dinv, csr_s, csr_n);

  // layer 1: aggregate x (256-wide), then GEMM + bias, then LN+ReLU
  agg256_kernel<<<N, 256, 0, stream>>>(x, csr_s, csr_n, offs, dinv, nullptr, ax);
  gemm_kernel<<<dim3((N + BM - 1) / BM, Ch / BN), 256, 0, stream>>>(ax, W1, b1, h1, N, Cin, Ch);
  ln_relu_kernel<512><<<N, 256, 0, stream>>>(h1, ga1, be1, h1);

  // layer 2: GEMM (no bias), aggregate (256-wide) + bias, LN+ReLU -> out
  gemm_kernel<<<dim3((N + BM - 1) / BM, Cout / BN), 256, 0, stream>>>(h1, W2, nullptr, ax, N, Ch, Cout);
  agg256_kernel<<<N, 256, 0, stream>>>(ax, csr_s, csr_n, offs, dinv, b2, h1);
  ln_relu_kernel<256><<<N, 256, 0, stream>>>(h1, ga2, be2, out);
}

// Round 4
// 222.029 us; speedup vs baseline: 1.5328x; 1.5328x over previous
//
#include <hip/hip_runtime.h>
#include <hip/hip_bf16.h>

// ---------------------------------------------------------------------------
// GCN 2-layer, bf16-MFMA GEMMs + f32 aggregation/LN.
//   ax  = A_norm @ x                (aggregate first, 256-wide; store bf16)
//   h1  = relu(LN(ax @ W1 + b1))    (MFMA bf16 GEMM; LN writes bf16)
//   h2  = h1 @ W2                   (MFMA bf16 GEMM, f32 out)
//   out = relu(LN(A_norm @ h2 + b2))
// ---------------------------------------------------------------------------

typedef __attribute__((ext_vector_type(8))) short bf16x8;
typedef __attribute__((ext_vector_type(4))) float f32x4;
typedef __attribute__((ext_vector_type(4))) unsigned short us4;

__device__ __forceinline__ unsigned short f2bf(float f) {  // RNE f32->bf16
  unsigned int x = __float_as_uint(f);
  return (unsigned short)((x + 0x7FFFu + ((x >> 16) & 1u)) >> 16);
}

__device__ __forceinline__ void wave_reduce2(float& s, float& ss) {
#pragma unroll
  for (int off = 32; off > 0; off >>= 1) {
    s  += __shfl_down(s, off, 64);
    ss += __shfl_down(ss, off, 64);
  }
}

// ------------------------------ preprocessing ------------------------------

__global__ __launch_bounds__(256) void deg_kernel(const int* __restrict__ dst, int E,
                                                  int* __restrict__ deg) {
  int e = blockIdx.x * 256 + threadIdx.x;
  if (e < E) atomicAdd(&deg[dst[e]], 1);
}

__global__ __launch_bounds__(256) void dinv_kernel(const int* __restrict__ deg, int N,
                                                   float* __restrict__ dinv) {
  int i = blockIdx.x * 256 + threadIdx.x;
  if (i < N) dinv[i] = rsqrtf((float)(deg[i] + 1));  // +1 self loop
}

// exclusive scan of deg[0..N) -> offsets[0..N], single block 1024, shfl-based.
__global__ __launch_bounds__(1024) void scan_kernel(const int* __restrict__ deg, int N,
                                                    int* __restrict__ offsets) {
  __shared__ int wsum[16];
  __shared__ int chunk_base;
  int tid = threadIdx.x;
  int lane = tid & 63, wid = tid >> 6;
  if (tid == 0) chunk_base = 0;
  __syncthreads();
  for (int c = 0; c < N; c += 1024) {
    int i = c + tid;
    int v = (i < N) ? deg[i] : 0;
    int s = v;  // inclusive scan within wave
#pragma unroll
    for (int off = 1; off < 64; off <<= 1) {
      int t = __shfl_up(s, off, 64);
      if (lane >= off) s += t;
    }
    if (lane == 63) wsum[wid] = s;
    __syncthreads();
    if (wid == 0 && lane < 16) {  // scan the 16 wave totals (exclusive)
      int ws = wsum[lane];
      int t = ws;
#pragma unroll
      for (int off = 1; off < 16; off <<= 1) {
        int u = __shfl_up(t, off, 64);
        if (lane >= off) t += u;
      }
      wsum[lane] = t - ws;
    }
    __syncthreads();
    if (i < N) offsets[i] = chunk_base + wsum[wid] + s - v;
    __syncthreads();
    if (tid == 1023) chunk_base += wsum[15] + s;  // total of this chunk
  }
  __syncthreads();
  if (tid == 0) offsets[N] = chunk_base;
}

__global__ __launch_bounds__(256) void fill_kernel(const int* __restrict__ src,
                                                   const int* __restrict__ dst, int E,
                                                   const int* __restrict__ offsets,
                                                   int* __restrict__ cursor,
                                                   const float* __restrict__ dinv,
                                                   int* __restrict__ csr_src,
                                                   float* __restrict__ csr_norm) {
  int e = blockIdx.x * 256 + threadIdx.x;
  if (e >= E) return;
  int s = src[e], d = dst[e];
  int p = offsets[d] + atomicAdd(&cursor[d], 1);
  csr_src[p]  = s;
  csr_norm[p] = dinv[s] * dinv[d];
}

// ------------------------------ aggregation --------------------------------
// one block per node, C=256. 4 waves each take every 4th edge; lane = channel/4
// (float4). LDS reduce across waves. OutT: float (f32x4 store) or ushort (bf16).

template <typename OutT>
__global__ __launch_bounds__(256) void agg_kernel(const float* __restrict__ H,
                                                  const int* __restrict__ csr_src,
                                                  const float* __restrict__ csr_norm,
                                                  const int* __restrict__ offsets,
                                                  const float* __restrict__ dinv,
                                                  const float* __restrict__ bias,
                                                  OutT* __restrict__ out) {
  __shared__ f32x4 sh[256];
  int node = blockIdx.x;
  int tid = threadIdx.x, w = tid >> 6, c4 = tid & 63;
  int p0 = offsets[node], p1 = offsets[node + 1];
  f32x4 acc = {0.f, 0.f, 0.f, 0.f};
  for (int p = p0 + w; p < p1; p += 4) {
    int s   = csr_src[p];
    float wt = csr_norm[p];
    f32x4 h = *(const f32x4*)&H[(size_t)s * 256 + c4 * 4];
    acc += h * wt;
  }
  sh[tid] = acc;
  __syncthreads();
  if (tid < 64) {
    f32x4 a = sh[tid] + sh[64 + tid] + sh[128 + tid] + sh[192 + tid];
    float dn = dinv[node];
    f32x4 self = *(const f32x4*)&H[(size_t)node * 256 + tid * 4];
    a += self * (dn * dn);
    if (bias) a += *(const f32x4*)&bias[tid * 4];
    if constexpr (sizeof(OutT) == 4) {
      *(f32x4*)&out[(size_t)node * 256 + tid * 4] = a;
    } else {
      us4 o;
      o.x = f2bf(a.x); o.y = f2bf(a.y); o.z = f2bf(a.z); o.w = f2bf(a.w);
      *(us4*)&out[(size_t)node * 256 + tid * 4] = o;
    }
  }
}

// --------------------------- weight transpose ------------------------------
// W[K][N] f32 -> Wt[N][K] bf16. K,N multiples of 32.
__global__ __launch_bounds__(256) void transpose_bf16(const float* __restrict__ W,
                                                      unsigned short* __restrict__ Wt,
                                                      int K, int N) {
  __shared__ unsigned short t[32][33];
  int n0 = blockIdx.x * 32, k0 = blockIdx.y * 32;
  int tx = threadIdx.x & 31, ty = threadIdx.x >> 5;  // ty 0..7
#pragma unroll
  for (int i = 0; i < 32; i += 8)
    t[ty + i][tx] = f2bf(W[(size_t)(k0 + ty + i) * N + n0 + tx]);
  __syncthreads();
#pragma unroll
  for (int i = 0; i < 32; i += 8)
    Wt[(size_t)(n0 + ty + i) * K + k0 + tx] = t[tx][ty + i];
}

// ------------------------------ MFMA GEMM ----------------------------------
// C[M,N] = A[M,K](bf16,row-major) @ Bt[N,K](bf16,row-major)^T (+bias), f32 out.
// 128x128 tile, BK=32, 4 waves 2x2 (64x64 each = 4x4 16x16 frags).
// LDS [128 rows][4 chunks of 16B]; chunk XOR-swizzled by (row>>1)&3 on both the
// pre-swizzled global_load_lds source and the ds_read (rule #21).

__global__ __launch_bounds__(256) void mfma_gemm_kernel(
    const unsigned short* __restrict__ A, const unsigned short* __restrict__ Bt,
    const float* __restrict__ bias, float* __restrict__ C, int M, int K, int N) {
  __shared__ unsigned short As[128 * 32];
  __shared__ unsigned short Bs[128 * 32];
  int tid = threadIdx.x;
  int lane = tid & 63, wid = tid >> 6;
  int bm = blockIdx.x * 128, bn = blockIdx.y * 128;
  int wm = (wid >> 1) * 64, wn = (wid & 1) * 64;
  int srow = tid >> 2;     // 0..63: staged row within a 64-row round
  int schunk = tid & 3;    // 16B chunk slot within the 64B row
  int frow = lane & 15, fk = lane >> 4;  // fragment row / k-chunk
  f32x4 acc[4][4] = {};

  for (int k0 = 0; k0 < K; k0 += 32) {
#pragma unroll
    for (int r = 0; r < 2; ++r) {
      int row = r * 64 + srow;
      int scA = schunk ^ ((row >> 1) & 3);
      int ga = bm + row; ga = ga < M ? ga : M - 1;
      int gb = bn + row; gb = gb < N ? gb : N - 1;
      const unsigned short* gA = A + (size_t)ga * K + k0 + scA * 8;
      const unsigned short* gB = Bt + (size_t)gb * K + k0 + scA * 8;
      __builtin_amdgcn_global_load_lds(
          (const __attribute__((address_space(1))) unsigned int*)(const void*)gA,
          (__attribute__((address_space(3))) unsigned int*)(void*)(As + (r * 64 + wid * 16) * 32),
          16, 0, 0);
      __builtin_amdgcn_global_load_lds(
          (const __attribute__((address_space(1))) unsigned int*)(const void*)gB,
          (__attribute__((address_space(3))) unsigned int*)(void*)(Bs + (r * 64 + wid * 16) * 32),
          16, 0, 0);
    }
    __syncthreads();
    bf16x8 af[4], bf[4];
#pragma unroll
    for (int mi = 0; mi < 4; ++mi) {
      int row = wm + mi * 16 + frow;
      int sc = fk ^ ((row >> 1) & 3);
      af[mi] = *(const bf16x8*)(As + row * 32 + sc * 8);
    }
#pragma unroll
    for (int ni = 0; ni < 4; ++ni) {
      int row = wn + ni * 16 + frow;
      int sc = fk ^ ((row >> 1) & 3);
      bf[ni] = *(const bf16x8*)(Bs + row * 32 + sc * 8);
    }
#pragma unroll
    for (int mi = 0; mi < 4; ++mi)
#pragma unroll
      for (int ni = 0; ni < 4; ++ni)
        acc[mi][ni] = __builtin_amdgcn_mfma_f32_16x16x32_bf16(af[mi], bf[ni], acc[mi][ni], 0, 0, 0);
    __syncthreads();
  }

  int row0 = bm + wm + (lane >> 4) * 4;
  int col0 = bn + wn + (lane & 15);
#pragma unroll
  for (int mi = 0; mi < 4; ++mi) {
#pragma unroll
    for (int ni = 0; ni < 4; ++ni) {
      int col = col0 + ni * 16;
      float bv = bias ? bias[col] : 0.0f;
#pragma unroll
      for (int r = 0; r < 4; ++r) {
        int row = row0 + mi * 16 + r;
        if (row < M) C[(size_t)row * N + col] = acc[mi][ni][r] + bv;
      }
    }
  }
}

// ------------------------------ LayerNorm ----------------------------------

template <int C, typename OutT>
__global__ __launch_bounds__(256) void ln_relu_kernel(const float* __restrict__ in,
                                                      const float* __restrict__ gamma,
                                                      const float* __restrict__ beta,
                                                      OutT* __restrict__ out) {
  int row = blockIdx.x;
  const float* p = in + (size_t)row * C;
  int tid = threadIdx.x;
  float v0 = p[tid];
  float v1 = (C == 512) ? p[tid + 256] : 0.0f;
  float s = v0 + v1;
  float ss = v0 * v0 + v1 * v1;
  wave_reduce2(s, ss);
  __shared__ float sh[8];
  int wid = tid >> 6;
  if ((tid & 63) == 0) { sh[wid] = s; sh[4 + wid] = ss; }
  __syncthreads();
  s  = sh[0] + sh[1] + sh[2] + sh[3];
  ss = sh[4] + sh[5] + sh[6] + sh[7];
  float mu = s * (1.0f / C);
  float var = ss * (1.0f / C) - mu * mu;
  float r = rsqrtf(var + 1e-5f);
  float o0 = fmaxf((v0 - mu) * r * gamma[tid] + beta[tid], 0.0f);
  if constexpr (sizeof(OutT) == 4) out[(size_t)row * C + tid] = o0;
  else                             out[(size_t)row * C + tid] = f2bf(o0);
  if (C == 512) {
    float o1 = fmaxf((v1 - mu) * r * gamma[tid + 256] + beta[tid + 256], 0.0f);
    if constexpr (sizeof(OutT) == 4) out[(size_t)row * C + tid + 256] = o1;
    else                             out[(size_t)row * C + tid + 256] = f2bf(o1);
  }
}

// ------------------------------ launcher -----------------------------------

extern "C" void kernel_launch(void* const* d_in, const int* in_sizes, int n_in,
                              void* d_out, int out_size, void* d_ws, size_t ws_size,
                              hipStream_t stream) {
  const float* x    = (const float*)d_in[0];
  const int*   ei   = (const int*)d_in[1];
  const float* W1   = (const float*)d_in[2];
  const float* b1   = (const float*)d_in[3];
  const float* ga1  = (const float*)d_in[4];
  const float* be1  = (const float*)d_in[5];
  const float* W2   = (const float*)d_in[6];
  const float* b2   = (const float*)d_in[7];
  const float* ga2  = (const float*)d_in[8];
  const float* be2  = (const float*)d_in[9];
  float* out = (float*)d_out;

  const int Ch   = in_sizes[3];        // 512
  const int Cout = in_sizes[7];        // 256
  const int Cin  = in_sizes[2] / Ch;   // 256
  const int N    = in_sizes[0] / Cin;  // 10000
  const int E    = in_sizes[1] / 2;    // 160000
  const int* srcp = ei;
  const int* dstp = ei + E;

  char* ws = (char*)d_ws;
  size_t off = 0;
  auto alloc = [&](size_t bytes) -> void* {
    off = (off + 255) & ~(size_t)255;
    void* p = ws + off;
    off += bytes;
    return p;
  };
  unsigned short* axb  = (unsigned short*)alloc((size_t)N * Cin * 2);  // agg1 out (bf16)
  float*          h1   = (float*)alloc((size_t)N * Ch * 4);            // gemm1 out; later agg2 out
  unsigned short* h1b  = (unsigned short*)alloc((size_t)N * Ch * 2);   // ln1 out (bf16)
  float*          h2   = (float*)alloc((size_t)N * Cout * 4);          // gemm2 out
  unsigned short* W1t  = (unsigned short*)alloc((size_t)Cin * Ch * 2);
  unsigned short* W2t  = (unsigned short*)alloc((size_t)Ch * Cout * 2);
  int*   deg   = (int*)alloc((size_t)N * 4);
  int*   curs  = (int*)alloc((size_t)N * 4);
  int*   offs  = (int*)alloc((size_t)(N + 1) * 4);
  float* dinv  = (float*)alloc((size_t)N * 4);
  int*   csr_s = (int*)alloc((size_t)E * 4);
  float* csr_n = (float*)alloc((size_t)E * 4);

  hipMemsetAsync(deg, 0, (size_t)N * 4, stream);
  hipMemsetAsync(curs, 0, (size_t)N * 4, stream);

  int gE = (E + 255) / 256;
  int gN = (N + 255) / 256;
  deg_kernel<<<gE, 256, 0, stream>>>(dstp, E, deg);
  dinv_kernel<<<gN, 256, 0, stream>>>(deg, N, dinv);
  scan_kernel<<<1, 1024, 0, stream>>>(deg, N, offs);
  fill_kernel<<<gE, 256, 0, stream>>>(srcp, dstp, E, offs, curs, dinv, csr_s, csr_n);

  // weight prep (independent; small)
  transpose_bf16<<<dim3(Ch / 32, Cin / 32), 256, 0, stream>>>(W1, W1t, Cin, Ch);
  transpose_bf16<<<dim3(Cout / 32, Ch / 32), 256, 0, stream>>>(W2, W2t, Ch, Cout);

  // layer 1
  agg_kernel<unsigned short><<<N, 256, 0, stream>>>(x, csr_s, csr_n, offs, dinv, nullptr, axb);
  mfma_gemm_kernel<<<dim3((N + 127) / 128, Ch / 128), 256, 0, stream>>>(axb, W1t, b1, h1, N, Cin, Ch);
  ln_relu_kernel<512, unsigned short><<<N, 256, 0, stream>>>(h1, ga1, be1, h1b);

  // layer 2
  mfma_gemm_kernel<<<dim3((N + 127) / 128, Cout / 128), 256, 0, stream>>>(h1b, W2t, nullptr, h2, N, Ch, Cout);
  agg_kernel<float><<<N, 256, 0, stream>>>(h2, csr_s, csr_n, offs, dinv, b2, h1);
  ln_relu_kernel<256, float><<<N, 256, 0, stream>>>(h1, ga2, be2, out);
}

// Round 5
// 208.364 us; speedup vs baseline: 1.6333x; 1.0656x over previous
//
#include <hip/hip_runtime.h>
#include <hip/hip_bf16.h>

// ---------------------------------------------------------------------------
// GCN 2-layer, bf16-MFMA GEMMs + bf16-gather aggregation.
//   xb  = bf16(x)
//   axb = A_norm @ xb               (bf16 gather, f32 accum, bf16 out)
//   h1  = axb @ W1 + b1             (MFMA)  ; h1b = bf16(relu(LN(h1)))
//   h2b = bf16(h1b @ W2)            (MFMA, bf16 out)
//   out = relu(LN(A_norm @ h2b + b2))   (agg fused with LN2+ReLU)
// Kernels: memset(deg), prep{convert x, deg count, W1t, W2t}, scan{+dinv,+curs},
//          fill, agg1, gemm1, ln1, gemm2, agg2+ln2.
// ---------------------------------------------------------------------------

typedef __attribute__((ext_vector_type(8))) short bf16x8;
typedef __attribute__((ext_vector_type(4))) float f32x4;
typedef __attribute__((ext_vector_type(4))) unsigned short us4;
typedef __attribute__((ext_vector_type(8))) unsigned short us8;

__device__ __forceinline__ unsigned short f2bf(float f) {  // RNE f32->bf16
  unsigned int x = __float_as_uint(f);
  return (unsigned short)((x + 0x7FFFu + ((x >> 16) & 1u)) >> 16);
}
__device__ __forceinline__ float bf2f(unsigned short u) {
  return __uint_as_float((unsigned int)u << 16);
}

// ------------------------------ prep (fused) -------------------------------
// block ranges: [0,nbx) convert x->bf16 ; [nbx,nbx+nbe) deg atomics ;
// then W1 transpose tiles ; then W2 transpose tiles.

__device__ __forceinline__ void transpose_tile(const float* __restrict__ W,
                                               unsigned short* __restrict__ Wt,
                                               int K, int N, int n0, int k0,
                                               unsigned short (*t)[33], int tid) {
  int tx = tid & 31, ty = tid >> 5;  // ty 0..7
#pragma unroll
  for (int i = 0; i < 32; i += 8)
    t[ty + i][tx] = f2bf(W[(size_t)(k0 + ty + i) * N + n0 + tx]);
  __syncthreads();
#pragma unroll
  for (int i = 0; i < 32; i += 8)
    Wt[(size_t)(n0 + ty + i) * K + k0 + tx] = t[tx][ty + i];
}

__global__ __launch_bounds__(256) void prep_kernel(
    const float* __restrict__ x, unsigned short* __restrict__ xb, long nelem,
    const int* __restrict__ dst, int E, int* __restrict__ deg,
    const float* __restrict__ W1, unsigned short* __restrict__ W1t,
    const float* __restrict__ W2, unsigned short* __restrict__ W2t,
    int Cin, int Ch, int Cout, int nbx, int nbe, int nbw1) {
  __shared__ unsigned short t[32][33];
  int bid = blockIdx.x;
  int tid = threadIdx.x;
  if (bid < nbx) {
    long i = ((long)bid * 256 + tid) * 8;
    if (i + 8 <= nelem) {
      f32x4 a = *(const f32x4*)&x[i];
      f32x4 b = *(const f32x4*)&x[i + 4];
      us8 o;
      o[0] = f2bf(a.x); o[1] = f2bf(a.y); o[2] = f2bf(a.z); o[3] = f2bf(a.w);
      o[4] = f2bf(b.x); o[5] = f2bf(b.y); o[6] = f2bf(b.z); o[7] = f2bf(b.w);
      *(us8*)&xb[i] = o;
    }
  } else if (bid < nbx + nbe) {
    int e = (bid - nbx) * 256 + tid;
    if (e < E) atomicAdd(&deg[dst[e]], 1);
  } else if (bid < nbx + nbe + nbw1) {
    int ti = bid - nbx - nbe;
    int w1w = Ch >> 5;  // tiles along N dim of W1
    transpose_tile(W1, W1t, Cin, Ch, (ti % w1w) * 32, (ti / w1w) * 32, t, tid);
  } else {
    int ti = bid - nbx - nbe - nbw1;
    int w2w = Cout >> 5;
    transpose_tile(W2, W2t, Ch, Cout, (ti % w2w) * 32, (ti / w2w) * 32, t, tid);
  }
}

// ---------------- scan (exclusive) + dinv + cursor init --------------------
__global__ __launch_bounds__(1024) void scan_kernel(const int* __restrict__ deg, int N,
                                                    int* __restrict__ offsets,
                                                    int* __restrict__ curs,
                                                    float* __restrict__ dinv) {
  __shared__ int wsum[16];
  __shared__ int chunk_base;
  int tid = threadIdx.x;
  int lane = tid & 63, wid = tid >> 6;
  if (tid == 0) chunk_base = 0;
  __syncthreads();
  for (int c = 0; c < N; c += 1024) {
    int i = c + tid;
    int v = (i < N) ? deg[i] : 0;
    if (i < N) dinv[i] = rsqrtf((float)(v + 1));  // +1 self loop
    int s = v;  // inclusive wave scan
#pragma unroll
    for (int off = 1; off < 64; off <<= 1) {
      int t = __shfl_up(s, off, 64);
      if (lane >= off) s += t;
    }
    if (lane == 63) wsum[wid] = s;
    __syncthreads();
    if (wid == 0 && lane < 16) {
      int ws = wsum[lane];
      int t = ws;
#pragma unroll
      for (int off = 1; off < 16; off <<= 1) {
        int u = __shfl_up(t, off, 64);
        if (lane >= off) t += u;
      }
      wsum[lane] = t - ws;
    }
    __syncthreads();
    if (i < N) {
      int o = chunk_base + wsum[wid] + s - v;
      offsets[i] = o;
      curs[i] = o;
    }
    __syncthreads();
    if (tid == 1023) chunk_base += wsum[15] + s;
  }
  __syncthreads();
  if (tid == 0) offsets[N] = chunk_base;
}

__global__ __launch_bounds__(256) void fill_kernel(const int* __restrict__ src,
                                                   const int* __restrict__ dst, int E,
                                                   int* __restrict__ curs,
                                                   const float* __restrict__ dinv,
                                                   int* __restrict__ csr_src,
                                                   float* __restrict__ csr_norm) {
  int e = blockIdx.x * 256 + threadIdx.x;
  if (e >= E) return;
  int s = src[e], d = dst[e];
  int p = atomicAdd(&curs[d], 1);
  csr_src[p]  = s;
  csr_norm[p] = dinv[s] * dinv[d];
}

// ------------------------------ aggregation --------------------------------
// one block per node, C=256, bf16 gather (us4 per lane), f32 accumulate.
// FUSE_LN: apply bias+LN+gamma/beta+ReLU, write f32. else write bf16.

template <bool FUSE_LN, typename OutT>
__global__ __launch_bounds__(256) void agg_kernel(const unsigned short* __restrict__ H,
                                                  const int* __restrict__ csr_src,
                                                  const float* __restrict__ csr_norm,
                                                  const int* __restrict__ offsets,
                                                  const float* __restrict__ dinv,
                                                  const float* __restrict__ bias,
                                                  const float* __restrict__ gamma,
                                                  const float* __restrict__ beta,
                                                  OutT* __restrict__ out) {
  __shared__ f32x4 sh[256];
  int node = blockIdx.x;
  int tid = threadIdx.x, w = tid >> 6, c4 = tid & 63;
  int p0 = offsets[node], p1 = offsets[node + 1];
  f32x4 acc = {0.f, 0.f, 0.f, 0.f};
  for (int p = p0 + w; p < p1; p += 4) {
    int s    = csr_src[p];
    float wt = csr_norm[p];
    us4 hv = *(const us4*)&H[(size_t)s * 256 + c4 * 4];
    acc.x = fmaf(bf2f(hv.x), wt, acc.x);
    acc.y = fmaf(bf2f(hv.y), wt, acc.y);
    acc.z = fmaf(bf2f(hv.z), wt, acc.z);
    acc.w = fmaf(bf2f(hv.w), wt, acc.w);
  }
  sh[tid] = acc;
  __syncthreads();
  if (tid < 64) {
    f32x4 a = sh[tid] + sh[64 + tid] + sh[128 + tid] + sh[192 + tid];
    float dn = dinv[node];
    float w2 = dn * dn;
    us4 sv = *(const us4*)&H[(size_t)node * 256 + tid * 4];
    a.x = fmaf(bf2f(sv.x), w2, a.x);
    a.y = fmaf(bf2f(sv.y), w2, a.y);
    a.z = fmaf(bf2f(sv.z), w2, a.z);
    a.w = fmaf(bf2f(sv.w), w2, a.w);
    if (bias) a += *(const f32x4*)&bias[tid * 4];
    if constexpr (FUSE_LN) {
      float s  = a.x + a.y + a.z + a.w;
      float ss = a.x * a.x + a.y * a.y + a.z * a.z + a.w * a.w;
#pragma unroll
      for (int off = 32; off > 0; off >>= 1) {
        s  += __shfl_xor(s, off, 64);
        ss += __shfl_xor(ss, off, 64);
      }
      float mu = s * (1.0f / 256.0f);
      float var = ss * (1.0f / 256.0f) - mu * mu;
      float r = rsqrtf(var + 1e-5f);
      f32x4 g  = *(const f32x4*)&gamma[tid * 4];
      f32x4 be = *(const f32x4*)&beta[tid * 4];
      f32x4 o;
      o.x = fmaxf((a.x - mu) * r * g.x + be.x, 0.f);
      o.y = fmaxf((a.y - mu) * r * g.y + be.y, 0.f);
      o.z = fmaxf((a.z - mu) * r * g.z + be.z, 0.f);
      o.w = fmaxf((a.w - mu) * r * g.w + be.w, 0.f);
      *(f32x4*)&out[(size_t)node * 256 + tid * 4] = o;
    } else {
      us4 o;
      o.x = f2bf(a.x); o.y = f2bf(a.y); o.z = f2bf(a.z); o.w = f2bf(a.w);
      *(us4*)&out[(size_t)node * 256 + tid * 4] = o;
    }
  }
}

// ------------------------------ MFMA GEMM ----------------------------------
// C[M,N] = A[M,K](bf16 rm) @ Bt[N,K](bf16 rm)^T (+bias). OutT f32 or bf16.
// 128x128 tile, BK=32, 4 waves 2x2. LDS chunk XOR-swizzle on both sides (#21).

template <typename OutT>
__global__ __launch_bounds__(256) void mfma_gemm_kernel(
    const unsigned short* __restrict__ A, const unsigned short* __restrict__ Bt,
    const float* __restrict__ bias, OutT* __restrict__ C, int M, int K, int N) {
  __shared__ unsigned short As[128 * 32];
  __shared__ unsigned short Bs[128 * 32];
  int tid = threadIdx.x;
  int lane = tid & 63, wid = tid >> 6;
  int bm = blockIdx.x * 128, bn = blockIdx.y * 128;
  int wm = (wid >> 1) * 64, wn = (wid & 1) * 64;
  int srow = tid >> 2;
  int schunk = tid & 3;
  int frow = lane & 15, fk = lane >> 4;
  f32x4 acc[4][4] = {};

  for (int k0 = 0; k0 < K; k0 += 32) {
#pragma unroll
    for (int r = 0; r < 2; ++r) {
      int row = r * 64 + srow;
      int scA = schunk ^ ((row >> 1) & 3);
      int ga = bm + row; ga = ga < M ? ga : M - 1;
      int gb = bn + row; gb = gb < N ? gb : N - 1;
      const unsigned short* gA = A + (size_t)ga * K + k0 + scA * 8;
      const unsigned short* gB = Bt + (size_t)gb * K + k0 + scA * 8;
      __builtin_amdgcn_global_load_lds(
          (const __attribute__((address_space(1))) unsigned int*)(const void*)gA,
          (__attribute__((address_space(3))) unsigned int*)(void*)(As + (r * 64 + wid * 16) * 32),
          16, 0, 0);
      __builtin_amdgcn_global_load_lds(
          (const __attribute__((address_space(1))) unsigned int*)(const void*)gB,
          (__attribute__((address_space(3))) unsigned int*)(void*)(Bs + (r * 64 + wid * 16) * 32),
          16, 0, 0);
    }
    __syncthreads();
    bf16x8 af[4], bf[4];
#pragma unroll
    for (int mi = 0; mi < 4; ++mi) {
      int row = wm + mi * 16 + frow;
      int sc = fk ^ ((row >> 1) & 3);
      af[mi] = *(const bf16x8*)(As + row * 32 + sc * 8);
    }
#pragma unroll
    for (int ni = 0; ni < 4; ++ni) {
      int row = wn + ni * 16 + frow;
      int sc = fk ^ ((row >> 1) & 3);
      bf[ni] = *(const bf16x8*)(Bs + row * 32 + sc * 8);
    }
#pragma unroll
    for (int mi = 0; mi < 4; ++mi)
#pragma unroll
      for (int ni = 0; ni < 4; ++ni)
        acc[mi][ni] = __builtin_amdgcn_mfma_f32_16x16x32_bf16(af[mi], bf[ni], acc[mi][ni], 0, 0, 0);
    __syncthreads();
  }

  int row0 = bm + wm + (lane >> 4) * 4;
  int col0 = bn + wn + (lane & 15);
#pragma unroll
  for (int mi = 0; mi < 4; ++mi) {
#pragma unroll
    for (int ni = 0; ni < 4; ++ni) {
      int col = col0 + ni * 16;
      float bv = bias ? bias[col] : 0.0f;
#pragma unroll
      for (int r = 0; r < 4; ++r) {
        int row = row0 + mi * 16 + r;
        if (row < M) {
          float v = acc[mi][ni][r] + bv;
          if constexpr (sizeof(OutT) == 4) C[(size_t)row * N + col] = v;
          else                             C[(size_t)row * N + col] = f2bf(v);
        }
      }
    }
  }
}

// ------------------------------ LayerNorm 1 --------------------------------

__global__ __launch_bounds__(256) void ln_relu512_kernel(const float* __restrict__ in,
                                                         const float* __restrict__ gamma,
                                                         const float* __restrict__ beta,
                                                         unsigned short* __restrict__ out) {
  int row = blockIdx.x;
  const float* p = in + (size_t)row * 512;
  int tid = threadIdx.x;
  float v0 = p[tid];
  float v1 = p[tid + 256];
  float s = v0 + v1;
  float ss = v0 * v0 + v1 * v1;
#pragma unroll
  for (int off = 32; off > 0; off >>= 1) {
    s  += __shfl_down(s, off, 64);
    ss += __shfl_down(ss, off, 64);
  }
  __shared__ float sh[8];
  int wid = tid >> 6;
  if ((tid & 63) == 0) { sh[wid] = s; sh[4 + wid] = ss; }
  __syncthreads();
  s  = sh[0] + sh[1] + sh[2] + sh[3];
  ss = sh[4] + sh[5] + sh[6] + sh[7];
  float mu = s * (1.0f / 512.0f);
  float var = ss * (1.0f / 512.0f) - mu * mu;
  float r = rsqrtf(var + 1e-5f);
  out[(size_t)row * 512 + tid]       = f2bf(fmaxf((v0 - mu) * r * gamma[tid] + beta[tid], 0.0f));
  out[(size_t)row * 512 + tid + 256] = f2bf(fmaxf((v1 - mu) * r * gamma[tid + 256] + beta[tid + 256], 0.0f));
}

// ------------------------------ launcher -----------------------------------

extern "C" void kernel_launch(void* const* d_in, const int* in_sizes, int n_in,
                              void* d_out, int out_size, void* d_ws, size_t ws_size,
                              hipStream_t stream) {
  const float* x    = (const float*)d_in[0];
  const int*   ei   = (const int*)d_in[1];
  const float* W1   = (const float*)d_in[2];
  const float* b1   = (const float*)d_in[3];
  const float* ga1  = (const float*)d_in[4];
  const float* be1  = (const float*)d_in[5];
  const float* W2   = (const float*)d_in[6];
  const float* b2   = (const float*)d_in[7];
  const float* ga2  = (const float*)d_in[8];
  const float* be2  = (const float*)d_in[9];
  float* out = (float*)d_out;

  const int Ch   = in_sizes[3];        // 512
  const int Cout = in_sizes[7];        // 256
  const int Cin  = in_sizes[2] / Ch;   // 256
  const int N    = in_sizes[0] / Cin;  // 10000
  const int E    = in_sizes[1] / 2;    // 160000
  const int* srcp = ei;
  const int* dstp = ei + E;

  char* ws = (char*)d_ws;
  size_t off = 0;
  auto alloc = [&](size_t bytes) -> void* {
    off = (off + 255) & ~(size_t)255;
    void* p = ws + off;
    off += bytes;
    return p;
  };
  unsigned short* xb   = (unsigned short*)alloc((size_t)N * Cin * 2);  // bf16(x)
  unsigned short* axb  = (unsigned short*)alloc((size_t)N * Cin * 2);  // agg1 out
  float*          h1   = (float*)alloc((size_t)N * Ch * 4);            // gemm1 out
  unsigned short* h1b  = (unsigned short*)alloc((size_t)N * Ch * 2);   // ln1 out
  unsigned short* h2b  = (unsigned short*)alloc((size_t)N * Cout * 2); // gemm2 out
  unsigned short* W1t  = (unsigned short*)alloc((size_t)Cin * Ch * 2);
  unsigned short* W2t  = (unsigned short*)alloc((size_t)Ch * Cout * 2);
  int*   deg   = (int*)alloc((size_t)N * 4);
  int*   curs  = (int*)alloc((size_t)N * 4);
  int*   offs  = (int*)alloc((size_t)(N + 1) * 4);
  float* dinv  = (float*)alloc((size_t)N * 4);
  int*   csr_s = (int*)alloc((size_t)E * 4);
  float* csr_n = (float*)alloc((size_t)E * 4);

  hipMemsetAsync(deg, 0, (size_t)N * 4, stream);

  long nelem = (long)N * Cin;
  int nbx  = (int)((nelem / 8 + 255) / 256);
  int nbe  = (E + 255) / 256;
  int nbw1 = (Cin / 32) * (Ch / 32);
  int nbw2 = (Ch / 32) * (Cout / 32);
  prep_kernel<<<nbx + nbe + nbw1 + nbw2, 256, 0, stream>>>(
      x, xb, nelem, dstp, E, deg, W1, W1t, W2, W2t, Cin, Ch, Cout, nbx, nbe, nbw1);
  scan_kernel<<<1, 1024, 0, stream>>>(deg, N, offs, curs, dinv);
  fill_kernel<<<nbe, 256, 0, stream>>>(srcp, dstp, E, curs, dinv, csr_s, csr_n);

  // layer 1
  agg_kernel<false, unsigned short><<<N, 256, 0, stream>>>(
      xb, csr_s, csr_n, offs, dinv, nullptr, nullptr, nullptr, axb);
  mfma_gemm_kernel<float><<<dim3((N + 127) / 128, Ch / 128), 256, 0, stream>>>(
      axb, W1t, b1, h1, N, Cin, Ch);
  ln_relu512_kernel<<<N, 256, 0, stream>>>(h1, ga1, be1, h1b);

  // layer 2
  mfma_gemm_kernel<unsigned short><<<dim3((N + 127) / 128, Cout / 128), 256, 0, stream>>>(
      h1b, W2t, nullptr, h2b, N, Ch, Cout);
  agg_kernel<true, float><<<N, 256, 0, stream>>>(
      h2b, csr_s, csr_n, offs, dinv, b2, ga2, be2, out);
}

// Round 7
// 204.873 us; speedup vs baseline: 1.6611x; 1.0170x over previous
//
#include <hip/hip_runtime.h>
#include <hip/hip_bf16.h>

// ---------------------------------------------------------------------------
// GCN 2-layer, bf16-MFMA GEMMs + bf16-gather aggregation (wave-per-node).
//   xb  = bf16(x)
//   axb = A_norm @ xb               (bf16 gather, f32 accum, bf16 out)
//   h1  = axb @ W1 + b1             (MFMA)  ; h1b = bf16(relu(LN(h1)))
//   h2b = bf16(h1b @ W2)            (MFMA, bf16 out)
//   out = relu(LN(A_norm @ h2b + b2))   (agg fused with LN2+ReLU)
// ---------------------------------------------------------------------------

typedef __attribute__((ext_vector_type(8))) short bf16x8;
typedef __attribute__((ext_vector_type(4))) float f32x4;
typedef __attribute__((ext_vector_type(4))) unsigned short us4;
typedef __attribute__((ext_vector_type(8))) unsigned short us8;

__device__ __forceinline__ unsigned short f2bf(float f) {  // RNE f32->bf16
  unsigned int x = __float_as_uint(f);
  return (unsigned short)((x + 0x7FFFu + ((x >> 16) & 1u)) >> 16);
}
__device__ __forceinline__ float bf2f(unsigned short u) {
  return __uint_as_float((unsigned int)u << 16);
}

// ------------------------------ prep (fused) -------------------------------
__device__ __forceinline__ void transpose_tile(const float* __restrict__ W,
                                               unsigned short* __restrict__ Wt,
                                               int K, int N, int n0, int k0,
                                               unsigned short (*t)[33], int tid) {
  int tx = tid & 31, ty = tid >> 5;  // ty 0..7
#pragma unroll
  for (int i = 0; i < 32; i += 8)
    t[ty + i][tx] = f2bf(W[(size_t)(k0 + ty + i) * N + n0 + tx]);
  __syncthreads();
#pragma unroll
  for (int i = 0; i < 32; i += 8)
    Wt[(size_t)(n0 + ty + i) * K + k0 + tx] = t[tx][ty + i];
}

__global__ __launch_bounds__(256) void prep_kernel(
    const float* __restrict__ x, unsigned short* __restrict__ xb, long nelem,
    const int* __restrict__ dst, int E, int* __restrict__ deg,
    const float* __restrict__ W1, unsigned short* __restrict__ W1t,
    const float* __restrict__ W2, unsigned short* __restrict__ W2t,
    int Cin, int Ch, int Cout, int nbx, int nbe, int nbw1) {
  __shared__ unsigned short t[32][33];
  int bid = blockIdx.x;
  int tid = threadIdx.x;
  if (bid < nbx) {
    long i = ((long)bid * 256 + tid) * 8;
    if (i + 8 <= nelem) {
      f32x4 a = *(const f32x4*)&x[i];
      f32x4 b = *(const f32x4*)&x[i + 4];
      us8 o;
      o[0] = f2bf(a.x); o[1] = f2bf(a.y); o[2] = f2bf(a.z); o[3] = f2bf(a.w);
      o[4] = f2bf(b.x); o[5] = f2bf(b.y); o[6] = f2bf(b.z); o[7] = f2bf(b.w);
      *(us8*)&xb[i] = o;
    }
  } else if (bid < nbx + nbe) {
    int e = (bid - nbx) * 256 + tid;
    if (e < E) atomicAdd(&deg[dst[e]], 1);
  } else if (bid < nbx + nbe + nbw1) {
    int ti = bid - nbx - nbe;
    int w1w = Ch >> 5;
    transpose_tile(W1, W1t, Cin, Ch, (ti % w1w) * 32, (ti / w1w) * 32, t, tid);
  } else {
    int ti = bid - nbx - nbe - nbw1;
    int w2w = Cout >> 5;
    transpose_tile(W2, W2t, Ch, Cout, (ti % w2w) * 32, (ti / w2w) * 32, t, tid);
  }
}

// ---------------- scan (exclusive) + dinv + cursor init --------------------
__global__ __launch_bounds__(1024) void scan_kernel(const int* __restrict__ deg, int N,
                                                    int* __restrict__ offsets,
                                                    int* __restrict__ curs,
                                                    float* __restrict__ dinv) {
  __shared__ int wsum[16];
  __shared__ int chunk_base;
  int tid = threadIdx.x;
  int lane = tid & 63, wid = tid >> 6;
  if (tid == 0) chunk_base = 0;
  __syncthreads();
  for (int c = 0; c < N; c += 1024) {
    int i = c + tid;
    int v = (i < N) ? deg[i] : 0;
    if (i < N) dinv[i] = rsqrtf((float)(v + 1));  // +1 self loop
    int s = v;
#pragma unroll
    for (int off = 1; off < 64; off <<= 1) {
      int t = __shfl_up(s, off, 64);
      if (lane >= off) s += t;
    }
    if (lane == 63) wsum[wid] = s;
    __syncthreads();
    if (wid == 0 && lane < 16) {
      int ws = wsum[lane];
      int t = ws;
#pragma unroll
      for (int off = 1; off < 16; off <<= 1) {
        int u = __shfl_up(t, off, 64);
        if (lane >= off) t += u;
      }
      wsum[lane] = t - ws;
    }
    __syncthreads();
    if (i < N) {
      int o = chunk_base + wsum[wid] + s - v;
      offsets[i] = o;
      curs[i] = o;
    }
    __syncthreads();
    if (tid == 1023) chunk_base += wsum[15] + s;
  }
  __syncthreads();
  if (tid == 0) offsets[N] = chunk_base;
}

__global__ __launch_bounds__(256) void fill_kernel(const int* __restrict__ src,
                                                   const int* __restrict__ dst, int E,
                                                   int* __restrict__ curs,
                                                   const float* __restrict__ dinv,
                                                   int* __restrict__ csr_src,
                                                   float* __restrict__ csr_norm) {
  int e = blockIdx.x * 256 + threadIdx.x;
  if (e >= E) return;
  int s = src[e], d = dst[e];
  int p = atomicAdd(&curs[d], 1);
  csr_src[p]  = s;
  csr_norm[p] = dinv[s] * dinv[d];
}

// ------------------------------ aggregation --------------------------------
// ONE WAVE per node: 64 lanes x us4 = full 256-ch bf16 row per gather.
// No LDS, no barriers; 4 nodes per 256-thread block; all edge gathers are
// independent loads the wave keeps in flight (latency-bound fix vs r5).

template <bool FUSE_LN, typename OutT>
__global__ __launch_bounds__(256) void agg_kernel(const unsigned short* __restrict__ H,
                                                  const int* __restrict__ csr_src,
                                                  const float* __restrict__ csr_norm,
                                                  const int* __restrict__ offsets,
                                                  const float* __restrict__ dinv,
                                                  const float* __restrict__ bias,
                                                  const float* __restrict__ gamma,
                                                  const float* __restrict__ beta,
                                                  OutT* __restrict__ out, int N) {
  int node = blockIdx.x * 4 + (threadIdx.x >> 6);
  if (node >= N) return;
  int lane = threadIdx.x & 63;
  int p0 = offsets[node], p1 = offsets[node + 1];
  f32x4 acc = {0.f, 0.f, 0.f, 0.f};
  for (int p = p0; p < p1; ++p) {
    int s    = csr_src[p];    // wave-uniform
    float wt = csr_norm[p];
    us4 hv = *(const us4*)&H[(size_t)s * 256 + lane * 4];
    acc.x = fmaf(bf2f(hv.x), wt, acc.x);
    acc.y = fmaf(bf2f(hv.y), wt, acc.y);
    acc.z = fmaf(bf2f(hv.z), wt, acc.z);
    acc.w = fmaf(bf2f(hv.w), wt, acc.w);
  }
  float dn = dinv[node];
  float w2 = dn * dn;
  us4 sv = *(const us4*)&H[(size_t)node * 256 + lane * 4];
  acc.x = fmaf(bf2f(sv.x), w2, acc.x);
  acc.y = fmaf(bf2f(sv.y), w2, acc.y);
  acc.z = fmaf(bf2f(sv.z), w2, acc.z);
  acc.w = fmaf(bf2f(sv.w), w2, acc.w);
  if (bias) acc += *(const f32x4*)&bias[lane * 4];
  if constexpr (FUSE_LN) {
    float s  = acc.x + acc.y + acc.z + acc.w;
    float ss = acc.x * acc.x + acc.y * acc.y + acc.z * acc.z + acc.w * acc.w;
#pragma unroll
    for (int off = 32; off > 0; off >>= 1) {
      s  += __shfl_xor(s, off, 64);
      ss += __shfl_xor(ss, off, 64);
    }
    float mu = s * (1.0f / 256.0f);
    float var = ss * (1.0f / 256.0f) - mu * mu;
    float r = rsqrtf(var + 1e-5f);
    f32x4 g  = *(const f32x4*)&gamma[lane * 4];
    f32x4 be = *(const f32x4*)&beta[lane * 4];
    f32x4 o;
    o.x = fmaxf((acc.x - mu) * r * g.x + be.x, 0.f);
    o.y = fmaxf((acc.y - mu) * r * g.y + be.y, 0.f);
    o.z = fmaxf((acc.z - mu) * r * g.z + be.z, 0.f);
    o.w = fmaxf((acc.w - mu) * r * g.w + be.w, 0.f);
    *(f32x4*)&out[(size_t)node * 256 + lane * 4] = o;
  } else {
    us4 o;
    o.x = f2bf(acc.x); o.y = f2bf(acc.y); o.z = f2bf(acc.z); o.w = f2bf(acc.w);
    *(us4*)&out[(size_t)node * 256 + lane * 4] = o;
  }
}

// ------------------------------ MFMA GEMM ----------------------------------
// C[M,N] = A[M,K](bf16 rm) @ Bt[N,K](bf16 rm)^T (+bias). OutT f32 or bf16.
// 64x128 tile (grid balance: gemm1 628 blocks, gemm2 314 on 256 CUs), BK=32,
// 4 waves 2x2, each 32x64 out. LDS chunk XOR-swizzle both sides (rule #21).

template <typename OutT>
__global__ __launch_bounds__(256) void mfma_gemm_kernel(
    const unsigned short* __restrict__ A, const unsigned short* __restrict__ Bt,
    const float* __restrict__ bias, OutT* __restrict__ C, int M, int K, int N) {
  __shared__ unsigned short As[64 * 32];
  __shared__ unsigned short Bs[128 * 32];
  int tid = threadIdx.x;
  int lane = tid & 63, wid = tid >> 6;
  int bm = blockIdx.x * 64, bn = blockIdx.y * 128;
  int wm = (wid >> 1) * 32, wn = (wid & 1) * 64;
  int srow = tid >> 2;
  int schunk = tid & 3;
  int frow = lane & 15, fk = lane >> 4;
  f32x4 acc[2][4] = {};

  for (int k0 = 0; k0 < K; k0 += 32) {
    {  // stage A: 64 rows, one round
      int row = srow;
      int scA = schunk ^ ((row >> 1) & 3);
      int ga = bm + row; ga = ga < M ? ga : M - 1;
      const unsigned short* gA = A + (size_t)ga * K + k0 + scA * 8;
      __builtin_amdgcn_global_load_lds(
          (const __attribute__((address_space(1))) unsigned int*)(const void*)gA,
          (__attribute__((address_space(3))) unsigned int*)(void*)(As + (wid * 16) * 32),
          16, 0, 0);
    }
#pragma unroll
    for (int r = 0; r < 2; ++r) {  // stage B: 128 rows, two rounds
      int row = r * 64 + srow;
      int scB = schunk ^ ((row >> 1) & 3);
      const unsigned short* gB = Bt + (size_t)(bn + row) * K + k0 + scB * 8;
      __builtin_amdgcn_global_load_lds(
          (const __attribute__((address_space(1))) unsigned int*)(const void*)gB,
          (__attribute__((address_space(3))) unsigned int*)(void*)(Bs + (r * 64 + wid * 16) * 32),
          16, 0, 0);
    }
    __syncthreads();
    bf16x8 af[2], bf[4];
#pragma unroll
    for (int mi = 0; mi < 2; ++mi) {
      int row = wm + mi * 16 + frow;
      int sc = fk ^ ((row >> 1) & 3);
      af[mi] = *(const bf16x8*)(As + row * 32 + sc * 8);
    }
#pragma unroll
    for (int ni = 0; ni < 4; ++ni) {
      int row = wn + ni * 16 + frow;
      int sc = fk ^ ((row >> 1) & 3);
      bf[ni] = *(const bf16x8*)(Bs + row * 32 + sc * 8);
    }
#pragma unroll
    for (int mi = 0; mi < 2; ++mi)
#pragma unroll
      for (int ni = 0; ni < 4; ++ni)
        acc[mi][ni] = __builtin_amdgcn_mfma_f32_16x16x32_bf16(af[mi], bf[ni], acc[mi][ni], 0, 0, 0);
    __syncthreads();
  }

  int row0 = bm + wm + fk * 4;
  int col0 = bn + wn + frow;
#pragma unroll
  for (int mi = 0; mi < 2; ++mi) {
#pragma unroll
    for (int ni = 0; ni < 4; ++ni) {
      int col = col0 + ni * 16;
      float bv = bias ? bias[col] : 0.0f;
#pragma unroll
      for (int r = 0; r < 4; ++r) {
        int row = row0 + mi * 16 + r;
        if (row < M) {
          float v = acc[mi][ni][r] + bv;
          if constexpr (sizeof(OutT) == 4) C[(size_t)row * N + col] = v;
          else                             C[(size_t)row * N + col] = f2bf(v);
        }
      }
    }
  }
}

// ------------------------------ LayerNorm 1 --------------------------------

__global__ __launch_bounds__(256) void ln_relu512_kernel(const float* __restrict__ in,
                                                         const float* __restrict__ gamma,
                                                         const float* __restrict__ beta,
                                                         unsigned short* __restrict__ out) {
  int row = blockIdx.x;
  const float* p = in + (size_t)row * 512;
  int tid = threadIdx.x;
  float v0 = p[tid];
  float v1 = p[tid + 256];
  float s = v0 + v1;
  float ss = v0 * v0 + v1 * v1;
#pragma unroll
  for (int off = 32; off > 0; off >>= 1) {
    s  += __shfl_down(s, off, 64);
    ss += __shfl_down(ss, off, 64);
  }
  __shared__ float sh[8];
  int wid = tid >> 6;
  if ((tid & 63) == 0) { sh[wid] = s; sh[4 + wid] = ss; }
  __syncthreads();
  s  = sh[0] + sh[1] + sh[2] + sh[3];
  ss = sh[4] + sh[5] + sh[6] + sh[7];
  float mu = s * (1.0f / 512.0f);
  float var = ss * (1.0f / 512.0f) - mu * mu;
  float r = rsqrtf(var + 1e-5f);
  out[(size_t)row * 512 + tid]       = f2bf(fmaxf((v0 - mu) * r * gamma[tid] + beta[tid], 0.0f));
  out[(size_t)row * 512 + tid + 256] = f2bf(fmaxf((v1 - mu) * r * gamma[tid + 256] + beta[tid + 256], 0.0f));
}

// ------------------------------ launcher -----------------------------------

extern "C" void kernel_launch(void* const* d_in, const int* in_sizes, int n_in,
                              void* d_out, int out_size, void* d_ws, size_t ws_size,
                              hipStream_t stream) {
  const float* x    = (const float*)d_in[0];
  const int*   ei   = (const int*)d_in[1];
  const float* W1   = (const float*)d_in[2];
  const float* b1   = (const float*)d_in[3];
  const float* ga1  = (const float*)d_in[4];
  const float* be1  = (const float*)d_in[5];
  const float* W2   = (const float*)d_in[6];
  const float* b2   = (const float*)d_in[7];
  const float* ga2  = (const float*)d_in[8];
  const float* be2  = (const float*)d_in[9];
  float* out = (float*)d_out;

  const int Ch   = in_sizes[3];        // 512
  const int Cout = in_sizes[7];        // 256
  const int Cin  = in_sizes[2] / Ch;   // 256
  const int N    = in_sizes[0] / Cin;  // 10000
  const int E    = in_sizes[1] / 2;    // 160000
  const int* srcp = ei;
  const int* dstp = ei + E;

  char* ws = (char*)d_ws;
  size_t off = 0;
  auto alloc = [&](size_t bytes) -> void* {
    off = (off + 255) & ~(size_t)255;
    void* p = ws + off;
    off += bytes;
    return p;
  };
  unsigned short* xb   = (unsigned short*)alloc((size_t)N * Cin * 2);
  unsigned short* axb  = (unsigned short*)alloc((size_t)N * Cin * 2);
  float*          h1   = (float*)alloc((size_t)N * Ch * 4);
  unsigned short* h1b  = (unsigned short*)alloc((size_t)N * Ch * 2);
  unsigned short* h2b  = (unsigned short*)alloc((size_t)N * Cout * 2);
  unsigned short* W1t  = (unsigned short*)alloc((size_t)Cin * Ch * 2);
  unsigned short* W2t  = (unsigned short*)alloc((size_t)Ch * Cout * 2);
  int*   deg   = (int*)alloc((size_t)N * 4);
  int*   curs  = (int*)alloc((size_t)N * 4);
  int*   offs  = (int*)alloc((size_t)(N + 1) * 4);
  float* dinv  = (float*)alloc((size_t)N * 4);
  int*   csr_s = (int*)alloc((size_t)E * 4);
  float* csr_n = (float*)alloc((size_t)E * 4);

  hipMemsetAsync(deg, 0, (size_t)N * 4, stream);

  long nelem = (long)N * Cin;
  int nbx  = (int)((nelem / 8 + 255) / 256);
  int nbe  = (E + 255) / 256;
  int nbw1 = (Cin / 32) * (Ch / 32);
  int nbw2 = (Ch / 32) * (Cout / 32);
  prep_kernel<<<nbx + nbe + nbw1 + nbw2, 256, 0, stream>>>(
      x, xb, nelem, dstp, E, deg, W1, W1t, W2, W2t, Cin, Ch, Cout, nbx, nbe, nbw1);
  scan_kernel<<<1, 1024, 0, stream>>>(deg, N, offs, curs, dinv);
  fill_kernel<<<nbe, 256, 0, stream>>>(srcp, dstp, E, curs, dinv, csr_s, csr_n);

  // layer 1
  agg_kernel<false, unsigned short><<<(N + 3) / 4, 256, 0, stream>>>(
      xb, csr_s, csr_n, offs, dinv, nullptr, nullptr, nullptr, axb, N);
  mfma_gemm_kernel<float><<<dim3((N + 63) / 64, Ch / 128), 256, 0, stream>>>(
      axb, W1t, b1, h1, N, Cin, Ch);
  ln_relu512_kernel<<<N, 256, 0, stream>>>(h1, ga1, be1, h1b);

  // layer 2
  mfma_gemm_kernel<unsigned short><<<dim3((N + 63) / 64, Cout / 128), 256, 0, stream>>>(
      h1b, W2t, nullptr, h2b, N, Ch, Cout);
  agg_kernel<true, float><<<(N + 3) / 4, 256, 0, stream>>>(
      h2b, csr_s, csr_n, offs, dinv, b2, ga2, be2, out, N);
}

// Round 12
// 189.904 us; speedup vs baseline: 1.7920x; 1.0788x over previous
//
#include <hip/hip_runtime.h>
#include <hip/hip_bf16.h>

// ---------------------------------------------------------------------------
// GCN 2-layer, bf16-MFMA GEMMs (LDS double-buffered) + pipelined bf16 gather.
//   xb  = bf16(x)
//   axb = A_norm @ xb               (2-deep pipelined gather, f32 accum)
//   h1  = axb @ W1 + b1             (MFMA, dbuf)  ; h1b = bf16(relu(LN(h1)))
//   h2b = bf16(h1b @ W2)            (MFMA, dbuf)
//   out = relu(LN(A_norm @ h2b + b2))   (agg fused with LN2+ReLU)
// CSR meta stored as int2 (src, norm-bits): one 8B wave-uniform load per edge.
// ---------------------------------------------------------------------------

typedef __attribute__((ext_vector_type(8))) short bf16x8;
typedef __attribute__((ext_vector_type(4))) float f32x4;
typedef __attribute__((ext_vector_type(4))) unsigned short us4;
typedef __attribute__((ext_vector_type(8))) unsigned short us8;

__device__ __forceinline__ unsigned short f2bf(float f) {  // RNE f32->bf16
  unsigned int x = __float_as_uint(f);
  return (unsigned short)((x + 0x7FFFu + ((x >> 16) & 1u)) >> 16);
}
__device__ __forceinline__ float bf2f(unsigned short u) {
  return __uint_as_float((unsigned int)u << 16);
}

// ------------------------------ prep (fused) -------------------------------
__device__ __forceinline__ void transpose_tile(const float* __restrict__ W,
                                               unsigned short* __restrict__ Wt,
                                               int K, int N, int n0, int k0,
                                               unsigned short (*t)[33], int tid) {
  int tx = tid & 31, ty = tid >> 5;  // ty 0..7
#pragma unroll
  for (int i = 0; i < 32; i += 8)
    t[ty + i][tx] = f2bf(W[(size_t)(k0 + ty + i) * N + n0 + tx]);
  __syncthreads();
#pragma unroll
  for (int i = 0; i < 32; i += 8)
    Wt[(size_t)(n0 + ty + i) * K + k0 + tx] = t[tx][ty + i];
  __syncthreads();
}

__global__ __launch_bounds__(256) void prep_kernel(
    const float* __restrict__ x, unsigned short* __restrict__ xb, long nelem,
    const int* __restrict__ dst, int E, int* __restrict__ deg,
    const float* __restrict__ W1, unsigned short* __restrict__ W1t,
    const float* __restrict__ W2, unsigned short* __restrict__ W2t,
    int Cin, int Ch, int Cout, int nbx, int nbe, int nbw1) {
  __shared__ unsigned short t[32][33];
  int bid = blockIdx.x, tid = threadIdx.x;
  if (bid < nbx) {
    long i = ((long)bid * 256 + tid) * 8;
    if (i + 8 <= nelem) {
      f32x4 a = *(const f32x4*)&x[i];
      f32x4 b = *(const f32x4*)&x[i + 4];
      us8 o;
      o[0] = f2bf(a.x); o[1] = f2bf(a.y); o[2] = f2bf(a.z); o[3] = f2bf(a.w);
      o[4] = f2bf(b.x); o[5] = f2bf(b.y); o[6] = f2bf(b.z); o[7] = f2bf(b.w);
      *(us8*)&xb[i] = o;
    }
  } else if (bid < nbx + nbe) {
    int e = (bid - nbx) * 256 + tid;
    if (e < E) atomicAdd(&deg[dst[e]], 1);
  } else if (bid < nbx + nbe + nbw1) {
    int ti = bid - nbx - nbe;
    int w = Ch >> 5;
    transpose_tile(W1, W1t, Cin, Ch, (ti % w) * 32, (ti / w) * 32, t, tid);
  } else {
    int ti = bid - nbx - nbe - nbw1;
    int w = Cout >> 5;
    transpose_tile(W2, W2t, Ch, Cout, (ti % w) * 32, (ti / w) * 32, t, tid);
  }
}

// ---------------- scan (exclusive) + dinv + cursor init --------------------
__global__ __launch_bounds__(1024) void scan_kernel(const int* __restrict__ deg, int N,
                                                    int* __restrict__ offsets,
                                                    int* __restrict__ curs,
                                                    float* __restrict__ dinv) {
  __shared__ int wsum[16];
  __shared__ int chunk_base;
  int tid = threadIdx.x;
  int lane = tid & 63, wid = tid >> 6;
  if (tid == 0) chunk_base = 0;
  __syncthreads();
  for (int c = 0; c < N; c += 1024) {
    int i = c + tid;
    int v = (i < N) ? deg[i] : 0;
    if (i < N) dinv[i] = rsqrtf((float)(v + 1));  // +1 self loop
    int s = v;
#pragma unroll
    for (int off = 1; off < 64; off <<= 1) {
      int t = __shfl_up(s, off, 64);
      if (lane >= off) s += t;
    }
    if (lane == 63) wsum[wid] = s;
    __syncthreads();
    if (wid == 0 && lane < 16) {
      int ws = wsum[lane];
      int t = ws;
#pragma unroll
      for (int off = 1; off < 16; off <<= 1) {
        int u = __shfl_up(t, off, 64);
        if (lane >= off) t += u;
      }
      wsum[lane] = t - ws;
    }
    __syncthreads();
    if (i < N) {
      int o = chunk_base + wsum[wid] + s - v;
      offsets[i] = o;
      curs[i] = o;
    }
    __syncthreads();
    if (tid == 1023) chunk_base += wsum[15] + s;
  }
  __syncthreads();
  if (tid == 0) offsets[N] = chunk_base;
}

__global__ __launch_bounds__(256) void fill_kernel(const int* __restrict__ src,
                                                   const int* __restrict__ dst, int E,
                                                   int* __restrict__ curs,
                                                   const float* __restrict__ dinv,
                                                   int2* __restrict__ csr_sn) {
  int e = blockIdx.x * 256 + threadIdx.x;
  if (e >= E) return;
  int s = src[e], d = dst[e];
  int p = atomicAdd(&curs[d], 1);
  csr_sn[p] = make_int2(s, __float_as_int(dinv[s] * dinv[d]));
}

// ------------------------------ aggregation --------------------------------
// ONE WAVE per node, 2-deep software-pipelined gather:
//   steady state: FMA(edge p) uses row loaded at iter p-1; meta loaded at p-2.

#define AGG_FMA(hv, wt)                      \
  acc.x = fmaf(bf2f((hv).x), (wt), acc.x);   \
  acc.y = fmaf(bf2f((hv).y), (wt), acc.y);   \
  acc.z = fmaf(bf2f((hv).z), (wt), acc.z);   \
  acc.w = fmaf(bf2f((hv).w), (wt), acc.w);

template <bool FUSE_LN, typename OutT>
__device__ __forceinline__ void agg_node(int node, int lane,
                                         const unsigned short* __restrict__ H,
                                         const int2* __restrict__ csr,
                                         const int* __restrict__ offs,
                                         const float* __restrict__ dinv,
                                         const float* __restrict__ bias,
                                         const float* __restrict__ gamma,
                                         const float* __restrict__ beta,
                                         OutT* __restrict__ out) {
  int p0 = offs[node], p1 = offs[node + 1];
  int n = p1 - p0;
  f32x4 acc = {0.f, 0.f, 0.f, 0.f};
  if (n > 0) {
    int2 e0 = csr[p0];
    us4 h0 = *(const us4*)&H[(size_t)e0.x * 256 + lane * 4];
    if (n > 1) {
      int2 e1 = csr[p0 + 1];
      for (int p = p0; p + 2 < p1; ++p) {
        us4 h1v = *(const us4*)&H[(size_t)e1.x * 256 + lane * 4];  // row(e1)
        int2 e2 = csr[p + 2];                                      // meta p+2
        AGG_FMA(h0, __int_as_float(e0.y));                         // consume e0
        e0 = e1; h0 = h1v; e1 = e2;
      }
      us4 h1v = *(const us4*)&H[(size_t)e1.x * 256 + lane * 4];
      AGG_FMA(h0, __int_as_float(e0.y));
      AGG_FMA(h1v, __int_as_float(e1.y));
    } else {
      AGG_FMA(h0, __int_as_float(e0.y));
    }
  }
  float dn = dinv[node];
  us4 sv = *(const us4*)&H[(size_t)node * 256 + lane * 4];
  AGG_FMA(sv, dn * dn);  // self loop
  if (bias) acc += *(const f32x4*)&bias[lane * 4];
  if constexpr (FUSE_LN) {
    float s  = acc.x + acc.y + acc.z + acc.w;
    float ss = acc.x * acc.x + acc.y * acc.y + acc.z * acc.z + acc.w * acc.w;
#pragma unroll
    for (int off = 32; off > 0; off >>= 1) {
      s  += __shfl_xor(s, off, 64);
      ss += __shfl_xor(ss, off, 64);
    }
    float mu = s * (1.0f / 256.0f);
    float var = ss * (1.0f / 256.0f) - mu * mu;
    float r = rsqrtf(var + 1e-5f);
    f32x4 g  = *(const f32x4*)&gamma[lane * 4];
    f32x4 be = *(const f32x4*)&beta[lane * 4];
    f32x4 o;
    o.x = fmaxf((acc.x - mu) * r * g.x + be.x, 0.f);
    o.y = fmaxf((acc.y - mu) * r * g.y + be.y, 0.f);
    o.z = fmaxf((acc.z - mu) * r * g.z + be.z, 0.f);
    o.w = fmaxf((acc.w - mu) * r * g.w + be.w, 0.f);
    *(f32x4*)&out[(size_t)node * 256 + lane * 4] = o;
  } else {
    us4 o;
    o.x = f2bf(acc.x); o.y = f2bf(acc.y); o.z = f2bf(acc.z); o.w = f2bf(acc.w);
    *(us4*)&out[(size_t)node * 256 + lane * 4] = o;
  }
}

template <bool FUSE_LN, typename OutT>
__global__ __launch_bounds__(256) void agg_kernel(const unsigned short* __restrict__ H,
                                                  const int2* __restrict__ csr,
                                                  const int* __restrict__ offs,
                                                  const float* __restrict__ dinv,
                                                  const float* __restrict__ bias,
                                                  const float* __restrict__ gamma,
                                                  const float* __restrict__ beta,
                                                  OutT* __restrict__ out, int N) {
  int node = blockIdx.x * 4 + (threadIdx.x >> 6);
  if (node >= N) return;
  agg_node<FUSE_LN, OutT>(node, threadIdx.x & 63, H, csr, offs, dinv, bias, gamma, beta, out);
}

// ------------------------------ MFMA GEMM ----------------------------------
// C[M,N] = A[M,K](bf16 rm) @ Bt[N,K](bf16 rm)^T (+bias). 64x128 tile, BK=32,
// 4 waves 2x2. LDS DOUBLE-BUFFERED (T3 2-phase): issue next-tile
// global_load_lds before compute; ONE __syncthreads per k-step (its implicit
// vmcnt(0) drains the prefetch). Chunk XOR-swizzle both sides (rule #21).

template <typename OutT>
__global__ __launch_bounds__(256) void mfma_gemm_kernel(
    const unsigned short* __restrict__ A, const unsigned short* __restrict__ Bt,
    const float* __restrict__ bias, OutT* __restrict__ C, int M, int K, int N) {
  __shared__ unsigned short As[2][64 * 32];
  __shared__ unsigned short Bs[2][128 * 32];
  int tid = threadIdx.x;
  int lane = tid & 63, wid = tid >> 6;
  int bm = blockIdx.x * 64, bn = blockIdx.y * 128;
  int wm = (wid >> 1) * 32, wn = (wid & 1) * 64;
  int srow = tid >> 2;
  int schunk = tid & 3;
  int frow = lane & 15, fk = lane >> 4;
  f32x4 acc[2][4] = {};

  // staging addresses (row-swizzled source, linear LDS dest per wave)
  int scA = schunk ^ ((srow >> 1) & 3);
  int gaA = bm + srow; gaA = gaA < M ? gaA : M - 1;
  const unsigned short* gA0 = A + (size_t)gaA * K + scA * 8;
  int rowB0 = srow, rowB1 = 64 + srow;
  int scB0 = schunk ^ ((rowB0 >> 1) & 3);
  int scB1 = schunk ^ ((rowB1 >> 1) & 3);
  const unsigned short* gB0 = Bt + (size_t)(bn + rowB0) * K + scB0 * 8;
  const unsigned short* gB1 = Bt + (size_t)(bn + rowB1) * K + scB1 * 8;

  auto stage = [&](int k0, unsigned short* Ad, unsigned short* Bd) {
    __builtin_amdgcn_global_load_lds(
        (const __attribute__((address_space(1))) unsigned int*)(const void*)(gA0 + k0),
        (__attribute__((address_space(3))) unsigned int*)(void*)(Ad + (wid * 16) * 32),
        16, 0, 0);
    __builtin_amdgcn_global_load_lds(
        (const __attribute__((address_space(1))) unsigned int*)(const void*)(gB0 + k0),
        (__attribute__((address_space(3))) unsigned int*)(void*)(Bd + (wid * 16) * 32),
        16, 0, 0);
    __builtin_amdgcn_global_load_lds(
        (const __attribute__((address_space(1))) unsigned int*)(const void*)(gB1 + k0),
        (__attribute__((address_space(3))) unsigned int*)(void*)(Bd + (64 + wid * 16) * 32),
        16, 0, 0);
  };

  int nk = K >> 5;
  stage(0, As[0], Bs[0]);
  __syncthreads();
  for (int k = 0; k < nk; ++k) {
    unsigned short* Ac = As[k & 1];
    unsigned short* Bc = Bs[k & 1];
    if (k + 1 < nk) stage((k + 1) << 5, As[(k + 1) & 1], Bs[(k + 1) & 1]);
    bf16x8 af[2], bf[4];
#pragma unroll
    for (int mi = 0; mi < 2; ++mi) {
      int row = wm + mi * 16 + frow;
      int sc = fk ^ ((row >> 1) & 3);
      af[mi] = *(const bf16x8*)(Ac + row * 32 + sc * 8);
    }
#pragma unroll
    for (int ni = 0; ni < 4; ++ni) {
      int row = wn + ni * 16 + frow;
      int sc = fk ^ ((row >> 1) & 3);
      bf[ni] = *(const bf16x8*)(Bc + row * 32 + sc * 8);
    }
#pragma unroll
    for (int mi = 0; mi < 2; ++mi)
#pragma unroll
      for (int ni = 0; ni < 4; ++ni)
        acc[mi][ni] = __builtin_amdgcn_mfma_f32_16x16x32_bf16(af[mi], bf[ni], acc[mi][ni], 0, 0, 0);
    __syncthreads();  // drains vmcnt: next buffers ready; LDS reuse safe
  }

  int row0 = bm + wm + fk * 4;
  int col0 = bn + wn + frow;
#pragma unroll
  for (int mi = 0; mi < 2; ++mi) {
#pragma unroll
    for (int ni = 0; ni < 4; ++ni) {
      int col = col0 + ni * 16;
      float bv = bias ? bias[col] : 0.0f;
#pragma unroll
      for (int r = 0; r < 4; ++r) {
        int row = row0 + mi * 16 + r;
        if (row < M) {
          float v = acc[mi][ni][r] + bv;
          if constexpr (sizeof(OutT) == 4) C[(size_t)row * N + col] = v;
          else                             C[(size_t)row * N + col] = f2bf(v);
        }
      }
    }
  }
}

// ------------------------------ LayerNorm 1 --------------------------------

__global__ __launch_bounds__(256) void ln_relu512_kernel(const float* __restrict__ in,
                                                         const float* __restrict__ gamma,
                                                         const float* __restrict__ beta,
                                                         unsigned short* __restrict__ out) {
  int row = blockIdx.x;
  const float* p = in + (size_t)row * 512;
  int tid = threadIdx.x;
  float v0 = p[tid];
  float v1 = p[tid + 256];
  float s = v0 + v1;
  float ss = v0 * v0 + v1 * v1;
#pragma unroll
  for (int off = 32; off > 0; off >>= 1) {
    s  += __shfl_down(s, off, 64);
    ss += __shfl_down(ss, off, 64);
  }
  __shared__ float sh[8];
  int wid = tid >> 6;
  if ((tid & 63) == 0) { sh[wid] = s; sh[4 + wid] = ss; }
  __syncthreads();
  s  = sh[0] + sh[1] + sh[2] + sh[3];
  ss = sh[4] + sh[5] + sh[6] + sh[7];
  float mu = s * (1.0f / 512.0f);
  float var = ss * (1.0f / 512.0f) - mu * mu;
  float r = rsqrtf(var + 1e-5f);
  out[(size_t)row * 512 + tid]       = f2bf(fmaxf((v0 - mu) * r * gamma[tid] + beta[tid], 0.0f));
  out[(size_t)row * 512 + tid + 256] = f2bf(fmaxf((v1 - mu) * r * gamma[tid + 256] + beta[tid + 256], 0.0f));
}

// ------------------------------ launcher -----------------------------------

extern "C" void kernel_launch(void* const* d_in, const int* in_sizes, int n_in,
                              void* d_out, int out_size, void* d_ws, size_t ws_size,
                              hipStream_t stream) {
  const float* x    = (const float*)d_in[0];
  const int*   ei   = (const int*)d_in[1];
  const float* W1   = (const float*)d_in[2];
  const float* b1   = (const float*)d_in[3];
  const float* ga1  = (const float*)d_in[4];
  const float* be1  = (const float*)d_in[5];
  const float* W2   = (const float*)d_in[6];
  const float* b2   = (const float*)d_in[7];
  const float* ga2  = (const float*)d_in[8];
  const float* be2  = (const float*)d_in[9];
  float* out = (float*)d_out;

  const int Ch   = in_sizes[3];        // 512
  const int Cout = in_sizes[7];        // 256
  const int Cin  = in_sizes[2] / Ch;   // 256
  const int N    = in_sizes[0] / Cin;  // 10000
  const int E    = in_sizes[1] / 2;    // 160000
  const int* srcp = ei;
  const int* dstp = ei + E;

  char* ws = (char*)d_ws;
  size_t off = 0;
  auto alloc = [&](size_t bytes) -> void* {
    off = (off + 255) & ~(size_t)255;
    void* p = ws + off;
    off += bytes;
    return p;
  };
  unsigned short* xb   = (unsigned short*)alloc((size_t)N * Cin * 2);
  unsigned short* axb  = (unsigned short*)alloc((size_t)N * Cin * 2);
  float*          h1   = (float*)alloc((size_t)N * Ch * 4);
  unsigned short* h1b  = (unsigned short*)alloc((size_t)N * Ch * 2);
  unsigned short* h2b  = (unsigned short*)alloc((size_t)N * Cout * 2);
  unsigned short* W1t  = (unsigned short*)alloc((size_t)Cin * Ch * 2);
  unsigned short* W2t  = (unsigned short*)alloc((size_t)Ch * Cout * 2);
  int*   deg   = (int*)alloc((size_t)N * 4);
  int*   curs  = (int*)alloc((size_t)N * 4);
  int*   offs  = (int*)alloc((size_t)(N + 1) * 4);
  float* dinv  = (float*)alloc((size_t)N * 4);
  int2*  csr   = (int2*)alloc((size_t)E * 8);

  hipMemsetAsync(deg, 0, (size_t)N * 4, stream);

  long nelem = (long)N * Cin;
  int nbx  = (int)((nelem / 8 + 255) / 256);
  int nbe  = (E + 255) / 256;
  int nbw1 = (Cin / 32) * (Ch / 32);
  int nbw2 = (Ch / 32) * (Cout / 32);
  prep_kernel<<<nbx + nbe + nbw1 + nbw2, 256, 0, stream>>>(
      x, xb, nelem, dstp, E, deg, W1, W1t, W2, W2t, Cin, Ch, Cout, nbx, nbe, nbw1);
  scan_kernel<<<1, 1024, 0, stream>>>(deg, N, offs, curs, dinv);
  fill_kernel<<<nbe, 256, 0, stream>>>(srcp, dstp, E, curs, dinv, csr);

  // layer 1
  agg_kernel<false, unsigned short><<<(N + 3) / 4, 256, 0, stream>>>(
      xb, csr, offs, dinv, nullptr, nullptr, nullptr, axb, N);
  mfma_gemm_kernel<float><<<dim3((N + 63) / 64, Ch / 128), 256, 0, stream>>>(
      axb, W1t, b1, h1, N, Cin, Ch);
  ln_relu512_kernel<<<N, 256, 0, stream>>>(h1, ga1, be1, h1b);

  // layer 2
  mfma_gemm_kernel<unsigned short><<<dim3((N + 63) / 64, Cout / 128), 256, 0, stream>>>(
      h1b, W2t, nullptr, h2b, N, Ch, Cout);
  agg_kernel<true, float><<<(N + 3) / 4, 256, 0, stream>>>(
      h2b, csr, offs, dinv, b2, ga2, be2, out, N);
}

// Round 13
// 182.148 us; speedup vs baseline: 1.8683x; 1.0426x over previous
//
#include <hip/hip_runtime.h>
#include <hip/hip_bf16.h>

// ---------------------------------------------------------------------------
// GCN 2-layer, symmetric GEMM-first structure:
//   xb  = bf16(x)
//   h1w = bf16(xb @ W1)                  (MFMA dbuf, bf16 out, no bias)
//   h1b = bf16(relu(LN(A_norm@h1w + b1)))  (agg 512-wide + LN1 fused)
//   h2w = bf16(h1b @ W2)                 (MFMA dbuf)
//   out = relu(LN(A_norm@h2w + b2))        (agg 256-wide + LN2 fused, f32)
// 8 graph nodes: memset, prep, scan, fill, gemm1, aggln1, gemm2, aggln2.
// CSR meta int2 (src, norm-bits); aggs wave-per-node, 2-deep pipelined.
// ---------------------------------------------------------------------------

typedef __attribute__((ext_vector_type(8))) short bf16x8;
typedef __attribute__((ext_vector_type(4))) float f32x4;
typedef __attribute__((ext_vector_type(4))) unsigned short us4;
typedef __attribute__((ext_vector_type(8))) unsigned short us8;

template <int CW> struct VecT;
template <> struct VecT<4> { typedef us4 T; };
template <> struct VecT<8> { typedef us8 T; };

__device__ __forceinline__ unsigned short f2bf(float f) {  // RNE f32->bf16
  unsigned int x = __float_as_uint(f);
  return (unsigned short)((x + 0x7FFFu + ((x >> 16) & 1u)) >> 16);
}
__device__ __forceinline__ float bf2f(unsigned short u) {
  return __uint_as_float((unsigned int)u << 16);
}

// ------------------------------ prep (fused) -------------------------------
__device__ __forceinline__ void transpose_tile(const float* __restrict__ W,
                                               unsigned short* __restrict__ Wt,
                                               int K, int N, int n0, int k0,
                                               unsigned short (*t)[33], int tid) {
  int tx = tid & 31, ty = tid >> 5;  // ty 0..7
#pragma unroll
  for (int i = 0; i < 32; i += 8)
    t[ty + i][tx] = f2bf(W[(size_t)(k0 + ty + i) * N + n0 + tx]);
  __syncthreads();
#pragma unroll
  for (int i = 0; i < 32; i += 8)
    Wt[(size_t)(n0 + ty + i) * K + k0 + tx] = t[tx][ty + i];
  __syncthreads();
}

__global__ __launch_bounds__(256) void prep_kernel(
    const float* __restrict__ x, unsigned short* __restrict__ xb, long nelem,
    const int* __restrict__ dst, int E, int* __restrict__ deg,
    const float* __restrict__ W1, unsigned short* __restrict__ W1t,
    const float* __restrict__ W2, unsigned short* __restrict__ W2t,
    int Cin, int Ch, int Cout, int nbx, int nbe, int nbw1) {
  __shared__ unsigned short t[32][33];
  int bid = blockIdx.x, tid = threadIdx.x;
  if (bid < nbx) {
    long i = ((long)bid * 256 + tid) * 8;
    if (i + 8 <= nelem) {
      f32x4 a = *(const f32x4*)&x[i];
      f32x4 b = *(const f32x4*)&x[i + 4];
      us8 o;
      o[0] = f2bf(a.x); o[1] = f2bf(a.y); o[2] = f2bf(a.z); o[3] = f2bf(a.w);
      o[4] = f2bf(b.x); o[5] = f2bf(b.y); o[6] = f2bf(b.z); o[7] = f2bf(b.w);
      *(us8*)&xb[i] = o;
    }
  } else if (bid < nbx + nbe) {
    int e = (bid - nbx) * 256 + tid;
    if (e < E) atomicAdd(&deg[dst[e]], 1);
  } else if (bid < nbx + nbe + nbw1) {
    int ti = bid - nbx - nbe;
    int w = Ch >> 5;
    transpose_tile(W1, W1t, Cin, Ch, (ti % w) * 32, (ti / w) * 32, t, tid);
  } else {
    int ti = bid - nbx - nbe - nbw1;
    int w = Cout >> 5;
    transpose_tile(W2, W2t, Ch, Cout, (ti % w) * 32, (ti / w) * 32, t, tid);
  }
}

// ---------------- scan (exclusive) + dinv + cursor init --------------------
__global__ __launch_bounds__(1024) void scan_kernel(const int* __restrict__ deg, int N,
                                                    int* __restrict__ offsets,
                                                    int* __restrict__ curs,
                                                    float* __restrict__ dinv) {
  __shared__ int wsum[16];
  __shared__ int chunk_base;
  int tid = threadIdx.x;
  int lane = tid & 63, wid = tid >> 6;
  if (tid == 0) chunk_base = 0;
  __syncthreads();
  for (int c = 0; c < N; c += 1024) {
    int i = c + tid;
    int v = (i < N) ? deg[i] : 0;
    if (i < N) dinv[i] = rsqrtf((float)(v + 1));  // +1 self loop
    int s = v;
#pragma unroll
    for (int off = 1; off < 64; off <<= 1) {
      int t = __shfl_up(s, off, 64);
      if (lane >= off) s += t;
    }
    if (lane == 63) wsum[wid] = s;
    __syncthreads();
    if (wid == 0 && lane < 16) {
      int ws = wsum[lane];
      int t = ws;
#pragma unroll
      for (int off = 1; off < 16; off <<= 1) {
        int u = __shfl_up(t, off, 64);
        if (lane >= off) t += u;
      }
      wsum[lane] = t - ws;
    }
    __syncthreads();
    if (i < N) {
      int o = chunk_base + wsum[wid] + s - v;
      offsets[i] = o;
      curs[i] = o;
    }
    __syncthreads();
    if (tid == 1023) chunk_base += wsum[15] + s;
  }
  __syncthreads();
  if (tid == 0) offsets[N] = chunk_base;
}

__global__ __launch_bounds__(256) void fill_kernel(const int* __restrict__ src,
                                                   const int* __restrict__ dst, int E,
                                                   int* __restrict__ curs,
                                                   const float* __restrict__ dinv,
                                                   int2* __restrict__ csr_sn) {
  int e = blockIdx.x * 256 + threadIdx.x;
  if (e >= E) return;
  int s = src[e], d = dst[e];
  int p = atomicAdd(&curs[d], 1);
  csr_sn[p] = make_int2(s, __float_as_int(dinv[s] * dinv[d]));
}

// --------------------- aggregation + bias + LN + ReLU ----------------------
// ONE WAVE per node; C channels (lane holds CW=C/64); 2-deep pipelined gather;
// fused bias + LayerNorm + ReLU epilogue. OutT: ushort(bf16) or float.

template <int C, typename OutT>
__global__ __launch_bounds__(256) void agg_ln_kernel(
    const unsigned short* __restrict__ H, const int2* __restrict__ csr,
    const int* __restrict__ offs, const float* __restrict__ dinv,
    const float* __restrict__ bias, const float* __restrict__ gamma,
    const float* __restrict__ beta, OutT* __restrict__ out, int N) {
  constexpr int CW = C / 64;
  typedef typename VecT<CW>::T usv;
  int node = blockIdx.x * 4 + (threadIdx.x >> 6);
  if (node >= N) return;
  int lane = threadIdx.x & 63;
  int p0 = offs[node], p1 = offs[node + 1];
  int n = p1 - p0;
  float acc[CW] = {};
  auto fma_row = [&](usv hv, float wt) {
#pragma unroll
    for (int j = 0; j < CW; ++j) acc[j] = fmaf(bf2f(hv[j]), wt, acc[j]);
  };
  if (n > 0) {
    int2 e0 = csr[p0];
    usv h0 = *(const usv*)&H[(size_t)e0.x * C + lane * CW];
    if (n > 1) {
      int2 e1 = csr[p0 + 1];
      for (int p = p0; p + 2 < p1; ++p) {
        usv h1v = *(const usv*)&H[(size_t)e1.x * C + lane * CW];  // row(e1)
        int2 e2 = csr[p + 2];                                     // meta p+2
        fma_row(h0, __int_as_float(e0.y));                        // consume e0
        e0 = e1; h0 = h1v; e1 = e2;
      }
      usv h1v = *(const usv*)&H[(size_t)e1.x * C + lane * CW];
      fma_row(h0, __int_as_float(e0.y));
      fma_row(h1v, __int_as_float(e1.y));
    } else {
      fma_row(h0, __int_as_float(e0.y));
    }
  }
  float dn = dinv[node];
  usv sv = *(const usv*)&H[(size_t)node * C + lane * CW];
  fma_row(sv, dn * dn);  // self loop
#pragma unroll
  for (int j = 0; j < CW; ++j) acc[j] += bias[lane * CW + j];
  float s = 0.f, ss = 0.f;
#pragma unroll
  for (int j = 0; j < CW; ++j) { s += acc[j]; ss += acc[j] * acc[j]; }
#pragma unroll
  for (int off = 32; off > 0; off >>= 1) {
    s  += __shfl_xor(s, off, 64);
    ss += __shfl_xor(ss, off, 64);
  }
  float mu = s * (1.0f / C);
  float var = ss * (1.0f / C) - mu * mu;
  float r = rsqrtf(var + 1e-5f);
  float o[CW];
#pragma unroll
  for (int j = 0; j < CW; ++j)
    o[j] = fmaxf((acc[j] - mu) * r * gamma[lane * CW + j] + beta[lane * CW + j], 0.f);
  if constexpr (sizeof(OutT) == 4) {
#pragma unroll
    for (int j = 0; j < CW; ++j) out[(size_t)node * C + lane * CW + j] = o[j];
  } else {
    usv ov;
#pragma unroll
    for (int j = 0; j < CW; ++j) ov[j] = f2bf(o[j]);
    *(usv*)&out[(size_t)node * C + lane * CW] = ov;
  }
}

// ------------------------------ MFMA GEMM ----------------------------------
// C[M,N] = A[M,K](bf16 rm) @ Bt[N,K](bf16 rm)^T, bf16 out, no bias.
// 64x128 tile, BK=32, 4 waves 2x2, LDS double-buffered (one barrier/k-step,
// implicit vmcnt(0) drain). Chunk XOR-swizzle both sides (rule #21).

__global__ __launch_bounds__(256) void mfma_gemm_kernel(
    const unsigned short* __restrict__ A, const unsigned short* __restrict__ Bt,
    unsigned short* __restrict__ C, int M, int K, int N) {
  __shared__ unsigned short As[2][64 * 32];
  __shared__ unsigned short Bs[2][128 * 32];
  int tid = threadIdx.x;
  int lane = tid & 63, wid = tid >> 6;
  int bm = blockIdx.x * 64, bn = blockIdx.y * 128;
  int wm = (wid >> 1) * 32, wn = (wid & 1) * 64;
  int srow = tid >> 2;
  int schunk = tid & 3;
  int frow = lane & 15, fk = lane >> 4;
  f32x4 acc[2][4] = {};

  int scA = schunk ^ ((srow >> 1) & 3);
  int gaA = bm + srow; gaA = gaA < M ? gaA : M - 1;
  const unsigned short* gA0 = A + (size_t)gaA * K + scA * 8;
  int rowB0 = srow, rowB1 = 64 + srow;
  int scB0 = schunk ^ ((rowB0 >> 1) & 3);
  int scB1 = schunk ^ ((rowB1 >> 1) & 3);
  const unsigned short* gB0 = Bt + (size_t)(bn + rowB0) * K + scB0 * 8;
  const unsigned short* gB1 = Bt + (size_t)(bn + rowB1) * K + scB1 * 8;

  auto stage = [&](int k0, unsigned short* Ad, unsigned short* Bd) {
    __builtin_amdgcn_global_load_lds(
        (const __attribute__((address_space(1))) unsigned int*)(const void*)(gA0 + k0),
        (__attribute__((address_space(3))) unsigned int*)(void*)(Ad + (wid * 16) * 32),
        16, 0, 0);
    __builtin_amdgcn_global_load_lds(
        (const __attribute__((address_space(1))) unsigned int*)(const void*)(gB0 + k0),
        (__attribute__((address_space(3))) unsigned int*)(void*)(Bd + (wid * 16) * 32),
        16, 0, 0);
    __builtin_amdgcn_global_load_lds(
        (const __attribute__((address_space(1))) unsigned int*)(const void*)(gB1 + k0),
        (__attribute__((address_space(3))) unsigned int*)(void*)(Bd + (64 + wid * 16) * 32),
        16, 0, 0);
  };

  int nk = K >> 5;
  stage(0, As[0], Bs[0]);
  __syncthreads();
  for (int k = 0; k < nk; ++k) {
    unsigned short* Ac = As[k & 1];
    unsigned short* Bc = Bs[k & 1];
    if (k + 1 < nk) stage((k + 1) << 5, As[(k + 1) & 1], Bs[(k + 1) & 1]);
    bf16x8 af[2], bf[4];
#pragma unroll
    for (int mi = 0; mi < 2; ++mi) {
      int row = wm + mi * 16 + frow;
      int sc = fk ^ ((row >> 1) & 3);
      af[mi] = *(const bf16x8*)(Ac + row * 32 + sc * 8);
    }
#pragma unroll
    for (int ni = 0; ni < 4; ++ni) {
      int row = wn + ni * 16 + frow;
      int sc = fk ^ ((row >> 1) & 3);
      bf[ni] = *(const bf16x8*)(Bc + row * 32 + sc * 8);
    }
#pragma unroll
    for (int mi = 0; mi < 2; ++mi)
#pragma unroll
      for (int ni = 0; ni < 4; ++ni)
        acc[mi][ni] = __builtin_amdgcn_mfma_f32_16x16x32_bf16(af[mi], bf[ni], acc[mi][ni], 0, 0, 0);
    __syncthreads();  // drains vmcnt: next buffers ready; LDS reuse safe
  }

  int row0 = bm + wm + fk * 4;
  int col0 = bn + wn + frow;
#pragma unroll
  for (int mi = 0; mi < 2; ++mi) {
#pragma unroll
    for (int ni = 0; ni < 4; ++ni) {
      int col = col0 + ni * 16;
#pragma unroll
      for (int r = 0; r < 4; ++r) {
        int row = row0 + mi * 16 + r;
        if (row < M) C[(size_t)row * N + col] = f2bf(acc[mi][ni][r]);
      }
    }
  }
}

// ------------------------------ launcher -----------------------------------

extern "C" void kernel_launch(void* const* d_in, const int* in_sizes, int n_in,
                              void* d_out, int out_size, void* d_ws, size_t ws_size,
                              hipStream_t stream) {
  const float* x    = (const float*)d_in[0];
  const int*   ei   = (const int*)d_in[1];
  const float* W1   = (const float*)d_in[2];
  const float* b1   = (const float*)d_in[3];
  const float* ga1  = (const float*)d_in[4];
  const float* be1  = (const float*)d_in[5];
  const float* W2   = (const float*)d_in[6];
  const float* b2   = (const float*)d_in[7];
  const float* ga2  = (const float*)d_in[8];
  const float* be2  = (const float*)d_in[9];
  float* out = (float*)d_out;

  const int Ch   = in_sizes[3];        // 512
  const int Cout = in_sizes[7];        // 256
  const int Cin  = in_sizes[2] / Ch;   // 256
  const int N    = in_sizes[0] / Cin;  // 10000
  const int E    = in_sizes[1] / 2;    // 160000
  const int* srcp = ei;
  const int* dstp = ei + E;

  char* ws = (char*)d_ws;
  size_t off = 0;
  auto alloc = [&](size_t bytes) -> void* {
    off = (off + 255) & ~(size_t)255;
    void* p = ws + off;
    off += bytes;
    return p;
  };
  unsigned short* xb   = (unsigned short*)alloc((size_t)N * Cin * 2);   // bf16(x)
  unsigned short* h1w  = (unsigned short*)alloc((size_t)N * Ch * 2);    // xb@W1
  unsigned short* h1b  = (unsigned short*)alloc((size_t)N * Ch * 2);    // aggln1 out
  unsigned short* h2w  = (unsigned short*)alloc((size_t)N * Cout * 2);  // h1b@W2
  unsigned short* W1t  = (unsigned short*)alloc((size_t)Cin * Ch * 2);
  unsigned short* W2t  = (unsigned short*)alloc((size_t)Ch * Cout * 2);
  int*   deg   = (int*)alloc((size_t)N * 4);
  int*   curs  = (int*)alloc((size_t)N * 4);
  int*   offs  = (int*)alloc((size_t)(N + 1) * 4);
  float* dinv  = (float*)alloc((size_t)N * 4);
  int2*  csr   = (int2*)alloc((size_t)E * 8);

  hipMemsetAsync(deg, 0, (size_t)N * 4, stream);

  long nelem = (long)N * Cin;
  int nbx  = (int)((nelem / 8 + 255) / 256);
  int nbe  = (E + 255) / 256;
  int nbw1 = (Cin / 32) * (Ch / 32);
  int nbw2 = (Ch / 32) * (Cout / 32);
  prep_kernel<<<nbx + nbe + nbw1 + nbw2, 256, 0, stream>>>(
      x, xb, nelem, dstp, E, deg, W1, W1t, W2, W2t, Cin, Ch, Cout, nbx, nbe, nbw1);
  scan_kernel<<<1, 1024, 0, stream>>>(deg, N, offs, curs, dinv);
  fill_kernel<<<nbe, 256, 0, stream>>>(srcp, dstp, E, curs, dinv, csr);

  // layer 1: GEMM-first, then fused agg+b1+LN1+ReLU (bf16 out)
  mfma_gemm_kernel<<<dim3((N + 63) / 64, Ch / 128), 256, 0, stream>>>(
      xb, W1t, h1w, N, Cin, Ch);
  agg_ln_kernel<512, unsigned short><<<(N + 3) / 4, 256, 0, stream>>>(
      h1w, csr, offs, dinv, b1, ga1, be1, h1b, N);

  // layer 2: GEMM, then fused agg+b2+LN2+ReLU (f32 out)
  mfma_gemm_kernel<<<dim3((N + 63) / 64, Cout / 128), 256, 0, stream>>>(
      h1b, W2t, h2w, N, Ch, Cout);
  agg_ln_kernel<256, float><<<(N + 3) / 4, 256, 0, stream>>>(
      h2w, csr, offs, dinv, b2, ga2, be2, out, N);
}